// Round 6
// baseline (187.827 us; speedup 1.0000x reference)
//
#include <hip/hip_runtime.h>

#define NPOS 4096
#define NB   64

typedef __bf16 bf8v __attribute__((ext_vector_type(8)));
typedef __bf16 bf4v __attribute__((ext_vector_type(4)));
typedef float  f4   __attribute__((ext_vector_type(4)));

__device__ __forceinline__ float sigm(float x)   { return 1.0f / (1.0f + __expf(-x)); }
__device__ __forceinline__ float tanh_f(float x) { return 1.0f - 2.0f / (1.0f + __expf(2.0f * x)); }

__device__ __forceinline__ f4 MF(bf8v a, bf8v b, f4 c) {
    return __builtin_amdgcn_mfma_f32_16x16x32_bf16(a, b, c, 0, 0, 0);
}

// ---------------- frag index map (1KB frags in d_ws) ----------------
// 0-19   W1pc [kb*4+t]   20-39 W1fc   40-59 W1yc        (kb=0..4, t=0..3)
// 60-67  W2pc [kb*4+t]   68-75 W2fc   76-83 W2yc        (kb=0..1)
// 84-91  ndW1            92-99 ndW2
// 100-123 Wih [kb*12+t]  124-147 Whh                    (t=0..11)
// 148-155 decW1          156-157 decW2 [kb]
// biases (f32 frags): 158 pcb1(4) 162 pcb2 166 fcb1 170 fcb2 174 ycb1 178 ycb2
// 182 ndb1 186 ndb2 190 bR(4) 194 bZ(4) 198 bIG(4) 202 bHG(4) 206 db1(4) 210 db2(1)
#define NFRAG 211

__global__ __launch_bounds__(64) void prep_kernel(
    const float* __restrict__ pcW1, const float* __restrict__ pcb1, const float* __restrict__ pcW2, const float* __restrict__ pcb2,
    const float* __restrict__ fcW1, const float* __restrict__ fcb1, const float* __restrict__ fcW2, const float* __restrict__ fcb2,
    const float* __restrict__ ycW1, const float* __restrict__ ycb1, const float* __restrict__ ycW2, const float* __restrict__ ycb2,
    const float* __restrict__ ndW1, const float* __restrict__ ndb1, const float* __restrict__ ndW2, const float* __restrict__ ndb2,
    const float* __restrict__ Wih,  const float* __restrict__ bih,  const float* __restrict__ Whh,  const float* __restrict__ bhh,
    const float* __restrict__ dW1,  const float* __restrict__ db1,  const float* __restrict__ dW2,  const float* __restrict__ db2,
    char* __restrict__ ws)
{
    const int f = blockIdx.x, l = threadIdx.x;
    const int sg = l >> 4, c16 = l & 15;
    char* dst = ws + (size_t)f * 1024 + (size_t)l * 16;

    if (f < 158) {
        const float* W = nullptr; int t = 0, kb = 0, ncol = 64, mlp = -1, kind = 0;
        if (f < 60)       { mlp = f / 20; int r = f % 20; kb = r >> 2; t = r & 3;
                            W = (mlp == 0 ? pcW1 : (mlp == 1 ? fcW1 : ycW1)); kind = 1; }
        else if (f < 84)  { int g = f - 60; int w = g >> 3; int r = g & 7; kb = r >> 2; t = r & 3;
                            W = (w == 0 ? pcW2 : (w == 1 ? fcW2 : ycW2)); }
        else if (f < 92)  { int r = f - 84; kb = r >> 2; t = r & 3; W = ndW1; }
        else if (f < 100) { int r = f - 92; kb = r >> 2; t = r & 3; W = ndW2; }
        else if (f < 124) { int r = f - 100; kb = r / 12; t = r % 12; W = Wih; ncol = 192; }
        else if (f < 148) { int r = f - 124; kb = r / 12; t = r % 12; W = Whh; ncol = 192; }
        else if (f < 156) { int r = f - 148; kb = r >> 2; t = r & 3; W = dW1; }
        else              { kb = f - 156; t = 0; W = dW2; kind = 2; }
        const int row = 16 * t + c16;
        bf8v v;
        #pragma unroll
        for (int j = 0; j < 8; ++j) {
            int k = kb * 32 + sg * 8 + j;
            float x;
            if (kind == 1 && kb == 4) {            // W1 message block: mlp owns cols mlp*4..+3
                int kk = k - 128 - mlp * 4;
                x = (kk >= 0 && kk < 4) ? W[(128 + kk) * 64 + row] : 0.f;
            } else if (kind == 2) {                // decW2 [64][4], rows 4..15 zero
                x = (row < 4) ? W[k * 4 + row] : 0.f;
            } else {
                x = W[k * ncol + row];
            }
            v[j] = (__bf16)x;
        }
        *(bf8v*)dst = v;
    } else {
        const int g = f - 158;
        f4 o;
        #pragma unroll
        for (int r = 0; r < 4; ++r) {
            float x = 0.f; int t;
            if (g < 32) {
                t = g & 3; int fi = 16 * t + 4 * sg + r;
                switch (g >> 2) {
                    case 0: x = pcb1[fi]; break; case 1: x = pcb2[fi]; break;
                    case 2: x = fcb1[fi]; break; case 3: x = fcb2[fi]; break;
                    case 4: x = ycb1[fi]; break; case 5: x = ycb2[fi]; break;
                    case 6: x = ndb1[fi]; break; default: x = ndb2[fi]; break;
                }
            } else if (g < 40) { t = g - 32; int fi = 16 * t + 4 * sg + r; x = bih[fi] + bhh[fi]; }
            else if (g < 44)   { t = g - 40; x = bih[128 + 16 * t + 4 * sg + r]; }
            else if (g < 48)   { t = g - 44; x = bhh[128 + 16 * t + 4 * sg + r]; }
            else if (g < 52)   { t = g - 48; x = db1[16 * t + 4 * sg + r]; }
            else               { x = (sg == 0) ? db2[r] : 0.f; }
            o[r] = x;
        }
        *(f4*)dst = o;
    }
}

// ---------------- LDS layout (bytes) ----------------
#define HXT 0              // 130 rows x 128B (pos n0-1 .. n0+128), swizzled
#define ACT 16640          // 128 rows x 128B (per-wave-private row ranges)
#define LDSZ 33024

__global__ __launch_bounds__(256, 3) void kgnn_main(
    const float* __restrict__ hx,  const float* __restrict__ pcm,
    const float* __restrict__ fcm, const float* __restrict__ ycm,
    const float* __restrict__ hy,
    const char*  __restrict__ ws,  float* __restrict__ out)
{
    __shared__ __align__(16) char LD[LDSZ];
    const int tid  = threadIdx.x;
    const int b    = blockIdx.x >> 5;
    const int tile = blockIdx.x & 31;
    const int n0   = tile * 128;
    const int baseH = b * 64 * NPOS;
    const int baseX = b * 4 * NPOS;

    // ---------------- staging: hx only (4x reuse: n-1, n, n+1, hprev) ----------------
    #pragma unroll
    for (int it = 0; it < 8; ++it) {
        const int idx = it * 256 + tid;
        const int pp = idx & 127, fg = idx >> 7;          // fg 0..15
        const int gn = n0 + pp;
        bf4v h;
        #pragma unroll
        for (int j = 0; j < 4; ++j) h[j] = (__bf16)hx[baseH + (4 * fg + j) * NPOS + gn];
        const int row = pp + 1;
        *(bf4v*)(LD + HXT + row * 128 + ((8 * fg) ^ ((row & 7) << 4))) = h;
    }
    // hx halo rows 0 and 129 (clamped)
    if (tid < 32) {
        const int side = tid & 1;
        const int fg = tid >> 1;
        const int row = side ? 129 : 0;
        const int gn = side ? min(n0 + 128, NPOS - 1) : max(n0 - 1, 0);
        bf4v h;
        #pragma unroll
        for (int j = 0; j < 4; ++j) h[j] = (__bf16)hx[baseH + (4 * fg + j) * NPOS + gn];
        *(bf4v*)(LD + HXT + row * 128 + ((8 * fg) ^ ((row & 7) << 4))) = h;
    }
    __syncthreads();

    const int lane = tid & 63, wid = tid >> 6;
    const int s = lane >> 4, q = lane & 15;
    const int Pv[2] = { wid * 32 + q, wid * 32 + 16 + q };

    auto ldA = [&](int frag) -> bf8v {
        return *(const bf8v*)(ws + ((size_t)frag << 10) + ((size_t)lane << 4));
    };
    auto ldBias = [&](int frag) -> f4 {
        return *(const f4*)(ws + ((size_t)frag << 10) + ((size_t)lane << 4));
    };
    auto ldB = [&](int base, int row, int h) -> bf8v {
        return *(const bf8v*)(LD + base + row * 128 + ((((h << 6) | (s << 4))) ^ ((row & 7) << 4)));
    };
    // hy B-frag direct from global: lane holds feats h*32+8s..+7 at position gn
    auto ldHy = [&](int gn, int h) -> bf8v {
        bf8v v;
        #pragma unroll
        for (int j = 0; j < 8; ++j)
            v[j] = (__bf16)hy[baseH + (h * 32 + 8 * s + j) * NPOS + gn];
        return v;
    };
    // message B-frag direct from global: feats 8s+j -> pcm 0-3 | fcm 4-7 | ycm 8-11 | 0
    auto ldMsg = [&](int gn) -> bf8v {
        bf8v v;
        #pragma unroll
        for (int j = 0; j < 8; ++j) {
            const int idx = 8 * s + j;
            float x = 0.f;
            if      (idx < 4)  x = pcm[baseX + idx * NPOS + gn];
            else if (idx < 8)  x = fcm[baseX + (idx - 4) * NPOS + gn];
            else if (idx < 12) x = ycm[baseX + (idx - 8) * NPOS + gn];
            v[j] = (__bf16)x;
        }
        return v;
    };
    auto stAct = [&](int row, int t, f4 v, bool relu) {
        bf4v h;
        #pragma unroll
        for (int r = 0; r < 4; ++r) {
            float x = v[r]; if (relu) x = fmaxf(x, 0.f);
            h[r] = (__bf16)x;
        }
        *(bf4v*)(LD + ACT + row * 128 + (((t << 5) | (s << 3)) ^ ((row & 7) << 4))) = h;
    };

    // ======== pc / fc / yc MLPs (c-fused: both 16-position groups per A-load) ========
    bf8v hxn0[2], hxn1[2], msgB[2];
    #pragma unroll
    for (int cc = 0; cc < 2; ++cc) {
        hxn0[cc] = ldB(HXT, Pv[cc] + 1, 0);
        hxn1[cc] = ldB(HXT, Pv[cc] + 1, 1);
        msgB[cc] = ldMsg(n0 + Pv[cc]);
    }
    f4 sum3[2][4];
    #pragma unroll
    for (int m = 0; m < 3; ++m) {
        bf8v e0[2], e1[2];
        #pragma unroll
        for (int cc = 0; cc < 2; ++cc) {
            if (m == 0)      { e0[cc] = ldB(HXT, Pv[cc],     0); e1[cc] = ldB(HXT, Pv[cc],     1); }
            else if (m == 1) { e0[cc] = ldB(HXT, Pv[cc] + 2, 0); e1[cc] = ldB(HXT, Pv[cc] + 2, 1); }
            else             { e0[cc] = ldHy(n0 + Pv[cc], 0);    e1[cc] = ldHy(n0 + Pv[cc], 1); }
        }
        const int w1 = m * 20, bb = 158 + m * 8;
        f4 a[2][4];
        #pragma unroll
        for (int t = 0; t < 4; ++t) { f4 bv = ldBias(bb + t); a[0][t] = bv; a[1][t] = bv; }
        #pragma unroll
        for (int t = 0; t < 4; ++t) { bf8v A = ldA(w1 + t);      a[0][t] = MF(A, e0[0],   a[0][t]); a[1][t] = MF(A, e0[1],   a[1][t]); }
        #pragma unroll
        for (int t = 0; t < 4; ++t) { bf8v A = ldA(w1 + 4 + t);  a[0][t] = MF(A, e1[0],   a[0][t]); a[1][t] = MF(A, e1[1],   a[1][t]); }
        #pragma unroll
        for (int t = 0; t < 4; ++t) { bf8v A = ldA(w1 + 8 + t);  a[0][t] = MF(A, hxn0[0], a[0][t]); a[1][t] = MF(A, hxn0[1], a[1][t]); }
        #pragma unroll
        for (int t = 0; t < 4; ++t) { bf8v A = ldA(w1 + 12 + t); a[0][t] = MF(A, hxn1[0], a[0][t]); a[1][t] = MF(A, hxn1[1], a[1][t]); }
        #pragma unroll
        for (int t = 0; t < 4; ++t) { bf8v A = ldA(w1 + 16 + t); a[0][t] = MF(A, msgB[0], a[0][t]); a[1][t] = MF(A, msgB[1], a[1][t]); }
        #pragma unroll
        for (int cc = 0; cc < 2; ++cc)
            #pragma unroll
            for (int t = 0; t < 4; ++t) stAct(Pv[cc], t, a[cc][t], true);

        bf8v c0[2] = { ldB(ACT, Pv[0], 0), ldB(ACT, Pv[1], 0) };
        bf8v c1[2] = { ldB(ACT, Pv[0], 1), ldB(ACT, Pv[1], 1) };
        const int w2 = 60 + m * 8;
        f4 a2[2][4];
        #pragma unroll
        for (int t = 0; t < 4; ++t) { f4 bv = ldBias(bb + 4 + t); a2[0][t] = bv; a2[1][t] = bv; }
        #pragma unroll
        for (int t = 0; t < 4; ++t) { bf8v A = ldA(w2 + t);     a2[0][t] = MF(A, c0[0], a2[0][t]); a2[1][t] = MF(A, c0[1], a2[1][t]); }
        #pragma unroll
        for (int t = 0; t < 4; ++t) { bf8v A = ldA(w2 + 4 + t); a2[0][t] = MF(A, c1[0], a2[0][t]); a2[1][t] = MF(A, c1[1], a2[1][t]); }
        #pragma unroll
        for (int cc = 0; cc < 2; ++cc)
            #pragma unroll
            for (int t = 0; t < 4; ++t)
                #pragma unroll
                for (int r = 0; r < 4; ++r) {
                    float x = fmaxf(a2[cc][t][r], 0.f);
                    if (m == 0) sum3[cc][t][r] = x; else sum3[cc][t][r] += x;
                }
    }

    // ======== nd MLP -> U (ends in ACT) ========
    #pragma unroll
    for (int cc = 0; cc < 2; ++cc)
        #pragma unroll
        for (int t = 0; t < 4; ++t) stAct(Pv[cc], t, sum3[cc][t], false);
    #pragma unroll
    for (int L = 0; L < 2; ++L) {
        bf8v u0[2] = { ldB(ACT, Pv[0], 0), ldB(ACT, Pv[1], 0) };
        bf8v u1[2] = { ldB(ACT, Pv[0], 1), ldB(ACT, Pv[1], 1) };
        const int wb = (L == 0) ? 84 : 92, bi = (L == 0) ? 182 : 186;
        f4 a[2][4];
        #pragma unroll
        for (int t = 0; t < 4; ++t) { f4 bv = ldBias(bi + t); a[0][t] = bv; a[1][t] = bv; }
        #pragma unroll
        for (int t = 0; t < 4; ++t) { bf8v A = ldA(wb + t);     a[0][t] = MF(A, u0[0], a[0][t]); a[1][t] = MF(A, u0[1], a[1][t]); }
        #pragma unroll
        for (int t = 0; t < 4; ++t) { bf8v A = ldA(wb + 4 + t); a[0][t] = MF(A, u1[0], a[0][t]); a[1][t] = MF(A, u1[1], a[1][t]); }
        #pragma unroll
        for (int cc = 0; cc < 2; ++cc)
            #pragma unroll
            for (int t = 0; t < 4; ++t) stAct(Pv[cc], t, a[cc][t], true);
    }

    // ======== GRU (sequential passes: hg -> r -> r*hg -> ig -> n -> z -> hnew) ========
    {
        bf8v uu0[2] = { ldB(ACT, Pv[0], 0), ldB(ACT, Pv[1], 0) };
        bf8v uu1[2] = { ldB(ACT, Pv[0], 1), ldB(ACT, Pv[1], 1) };
        bf8v hh0[2] = { ldB(HXT, Pv[0] + 1, 0), ldB(HXT, Pv[1] + 1, 0) };
        bf8v hh1[2] = { ldB(HXT, Pv[0] + 1, 1), ldB(HXT, Pv[1] + 1, 1) };

        f4 g[2][4];
        #pragma unroll
        for (int t = 0; t < 4; ++t) { f4 bv = ldBias(202 + t); g[0][t] = bv; g[1][t] = bv; }
        #pragma unroll
        for (int t = 0; t < 4; ++t) { bf8v A = ldA(132 + t); g[0][t] = MF(A, hh0[0], g[0][t]); g[1][t] = MF(A, hh0[1], g[1][t]); }
        #pragma unroll
        for (int t = 0; t < 4; ++t) { bf8v A = ldA(144 + t); g[0][t] = MF(A, hh1[0], g[0][t]); g[1][t] = MF(A, hh1[1], g[1][t]); }

        {
            f4 rr[2][4];
            #pragma unroll
            for (int t = 0; t < 4; ++t) { f4 bv = ldBias(190 + t); rr[0][t] = bv; rr[1][t] = bv; }
            #pragma unroll
            for (int t = 0; t < 4; ++t) { bf8v A = ldA(100 + t); rr[0][t] = MF(A, uu0[0], rr[0][t]); rr[1][t] = MF(A, uu0[1], rr[1][t]); }
            #pragma unroll
            for (int t = 0; t < 4; ++t) { bf8v A = ldA(112 + t); rr[0][t] = MF(A, uu1[0], rr[0][t]); rr[1][t] = MF(A, uu1[1], rr[1][t]); }
            #pragma unroll
            for (int t = 0; t < 4; ++t) { bf8v A = ldA(124 + t); rr[0][t] = MF(A, hh0[0], rr[0][t]); rr[1][t] = MF(A, hh0[1], rr[1][t]); }
            #pragma unroll
            for (int t = 0; t < 4; ++t) { bf8v A = ldA(136 + t); rr[0][t] = MF(A, hh1[0], rr[0][t]); rr[1][t] = MF(A, hh1[1], rr[1][t]); }
            #pragma unroll
            for (int cc = 0; cc < 2; ++cc)
                #pragma unroll
                for (int t = 0; t < 4; ++t)
                    #pragma unroll
                    for (int r = 0; r < 4; ++r) g[cc][t][r] = sigm(rr[cc][t][r]) * g[cc][t][r];
        }
        {
            f4 gi[2][4];
            #pragma unroll
            for (int t = 0; t < 4; ++t) { f4 bv = ldBias(198 + t); gi[0][t] = bv; gi[1][t] = bv; }
            #pragma unroll
            for (int t = 0; t < 4; ++t) { bf8v A = ldA(108 + t); gi[0][t] = MF(A, uu0[0], gi[0][t]); gi[1][t] = MF(A, uu0[1], gi[1][t]); }
            #pragma unroll
            for (int t = 0; t < 4; ++t) { bf8v A = ldA(120 + t); gi[0][t] = MF(A, uu1[0], gi[0][t]); gi[1][t] = MF(A, uu1[1], gi[1][t]); }
            #pragma unroll
            for (int cc = 0; cc < 2; ++cc)
                #pragma unroll
                for (int t = 0; t < 4; ++t)
                    #pragma unroll
                    for (int r = 0; r < 4; ++r) g[cc][t][r] = tanh_f(gi[cc][t][r] + g[cc][t][r]);   // n-gate
        }
        f4 zz[2][4];
        #pragma unroll
        for (int t = 0; t < 4; ++t) { f4 bv = ldBias(194 + t); zz[0][t] = bv; zz[1][t] = bv; }
        #pragma unroll
        for (int t = 0; t < 4; ++t) { bf8v A = ldA(104 + t); zz[0][t] = MF(A, uu0[0], zz[0][t]); zz[1][t] = MF(A, uu0[1], zz[1][t]); }
        #pragma unroll
        for (int t = 0; t < 4; ++t) { bf8v A = ldA(116 + t); zz[0][t] = MF(A, uu1[0], zz[0][t]); zz[1][t] = MF(A, uu1[1], zz[1][t]); }
        #pragma unroll
        for (int t = 0; t < 4; ++t) { bf8v A = ldA(128 + t); zz[0][t] = MF(A, hh0[0], zz[0][t]); zz[1][t] = MF(A, hh0[1], zz[1][t]); }
        #pragma unroll
        for (int t = 0; t < 4; ++t) { bf8v A = ldA(140 + t); zz[0][t] = MF(A, hh1[0], zz[0][t]); zz[1][t] = MF(A, hh1[1], zz[1][t]); }

        float* __restrict__ outH = out + NB * 4 * NPOS + baseH;
        #pragma unroll
        for (int cc = 0; cc < 2; ++cc) {
            const int hrow = Pv[cc] + 1;
            const int gn = n0 + Pv[cc];
            #pragma unroll
            for (int t = 0; t < 4; ++t) {
                bf4v hp4 = *(const bf4v*)(LD + HXT + hrow * 128 +
                                          (((t << 5) | (s << 3)) ^ ((hrow & 7) << 4)));
                bf4v hnb;
                #pragma unroll
                for (int r = 0; r < 4; ++r) {
                    float z  = sigm(zz[cc][t][r]);
                    float nn = g[cc][t][r];
                    float hp = (float)hp4[r];
                    float hn = nn + z * (hp - nn);
                    outH[(16 * t + 4 * s + r) * NPOS + gn] = hn;
                    hnb[r] = (__bf16)hn;
                }
                *(bf4v*)(LD + ACT + Pv[cc] * 128 + (((t << 5) | (s << 3)) ^ ((Pv[cc] & 7) << 4))) = hnb;
            }
        }
    }

    // ======== decoder ========
    {
        bf8v d0[2] = { ldB(ACT, Pv[0], 0), ldB(ACT, Pv[1], 0) };
        bf8v d1[2] = { ldB(ACT, Pv[0], 1), ldB(ACT, Pv[1], 1) };
        f4 a[2][4];
        #pragma unroll
        for (int t = 0; t < 4; ++t) { f4 bv = ldBias(206 + t); a[0][t] = bv; a[1][t] = bv; }
        #pragma unroll
        for (int t = 0; t < 4; ++t) { bf8v A = ldA(148 + t); a[0][t] = MF(A, d0[0], a[0][t]); a[1][t] = MF(A, d0[1], a[1][t]); }
        #pragma unroll
        for (int t = 0; t < 4; ++t) { bf8v A = ldA(152 + t); a[0][t] = MF(A, d1[0], a[0][t]); a[1][t] = MF(A, d1[1], a[1][t]); }
        #pragma unroll
        for (int cc = 0; cc < 2; ++cc)
            #pragma unroll
            for (int t = 0; t < 4; ++t) stAct(Pv[cc], t, a[cc][t], true);

        bf8v e0[2] = { ldB(ACT, Pv[0], 0), ldB(ACT, Pv[1], 0) };
        bf8v e1[2] = { ldB(ACT, Pv[0], 1), ldB(ACT, Pv[1], 1) };
        f4 ep[2];
        { f4 bv = ldBias(210); ep[0] = bv; ep[1] = bv; }
        { bf8v A = ldA(156); ep[0] = MF(A, e0[0], ep[0]); ep[1] = MF(A, e0[1], ep[1]); }
        { bf8v A = ldA(157); ep[0] = MF(A, e1[0], ep[0]); ep[1] = MF(A, e1[1], ep[1]); }
        if (s == 0) {
            #pragma unroll
            for (int cc = 0; cc < 2; ++cc) {
                const int gn = n0 + Pv[cc];
                #pragma unroll
                for (int r = 0; r < 4; ++r) out[baseX + r * NPOS + gn] = ep[cc][r];
            }
        }
    }
}

extern "C" void kernel_launch(void* const* d_in, const int* in_sizes, int n_in,
                              void* d_out, int out_size, void* d_ws, size_t ws_size,
                              hipStream_t stream) {
    const float* hx   = (const float*)d_in[0];
    const float* pcm  = (const float*)d_in[1];
    const float* fcm  = (const float*)d_in[2];
    const float* ycm  = (const float*)d_in[3];
    const float* hy   = (const float*)d_in[4];

    prep_kernel<<<dim3(NFRAG), dim3(64), 0, stream>>>(
        (const float*)d_in[5],  (const float*)d_in[6],  (const float*)d_in[7],  (const float*)d_in[8],
        (const float*)d_in[9],  (const float*)d_in[10], (const float*)d_in[11], (const float*)d_in[12],
        (const float*)d_in[13], (const float*)d_in[14], (const float*)d_in[15], (const float*)d_in[16],
        (const float*)d_in[17], (const float*)d_in[18], (const float*)d_in[19], (const float*)d_in[20],
        (const float*)d_in[21], (const float*)d_in[22], (const float*)d_in[23], (const float*)d_in[24],
        (const float*)d_in[25], (const float*)d_in[26], (const float*)d_in[27], (const float*)d_in[28],
        (char*)d_ws);

    kgnn_main<<<dim3(NB * 32), dim3(256), 0, stream>>>(
        hx, pcm, fcm, ycm, hy, (const char*)d_ws, (float*)d_out);
}

// Round 7
// 117.508 us; speedup vs baseline: 1.5984x; 1.5984x over previous
//
#include <hip/hip_runtime.h>

#define NPOS 4096
#define NB   64

typedef __bf16 bf8v __attribute__((ext_vector_type(8)));
typedef __bf16 bf4v __attribute__((ext_vector_type(4)));
typedef float  f4   __attribute__((ext_vector_type(4)));

__device__ __forceinline__ float sigm(float x)   { return 1.0f / (1.0f + __expf(-x)); }
__device__ __forceinline__ float tanh_f(float x) { return 1.0f - 2.0f / (1.0f + __expf(2.0f * x)); }

__device__ __forceinline__ f4 MF(bf8v a, bf8v b, f4 c) {
    return __builtin_amdgcn_mfma_f32_16x16x32_bf16(a, b, c, 0, 0, 0);
}

// ---------------- phase-contiguous frag layout in d_ws (1KB frags) ----------------
// P0/P1/P2 (pc/fc/yc) base m*36:
//   +0..19  W1 [kb*4+t] kb=0..4 (kb4 = message block, per-mlp masked)
//   +20..27 W2 [kb*4+t] kb=0..1
//   +28..31 b1[t]   +32..35 b2[t]
// P3 (nd) base 108: +0..7 ndW1, +8..15 ndW2, +16..19 ndb1, +20..23 ndb2
// P4 (GRU-A) base 132: +0..7 Whh[:,128:] (hg), +8..15 Wih[:,0:64] (r),
//   +16..23 Whh[:,0:64] (r), +24..27 bHG, +28..31 bR(=bih+bhh [0:64])
// P5 (GRU-B) base 164: +0..7 Wih[:,128:] (ig), +8..15 Wih[:,64:128] (z),
//   +16..23 Whh[:,64:128] (z), +24..27 bIG, +28..31 bZ(=bih+bhh [64:128])
// P6 (dec) base 196: +0..7 dW1, +8..9 dW2, +10..13 db1, +14 db2
#define NFRAG 211

__global__ __launch_bounds__(64) void prep_kernel(
    const float* __restrict__ pcW1, const float* __restrict__ pcb1, const float* __restrict__ pcW2, const float* __restrict__ pcb2,
    const float* __restrict__ fcW1, const float* __restrict__ fcb1, const float* __restrict__ fcW2, const float* __restrict__ fcb2,
    const float* __restrict__ ycW1, const float* __restrict__ ycb1, const float* __restrict__ ycW2, const float* __restrict__ ycb2,
    const float* __restrict__ ndW1, const float* __restrict__ ndb1, const float* __restrict__ ndW2, const float* __restrict__ ndb2,
    const float* __restrict__ Wih,  const float* __restrict__ bih,  const float* __restrict__ Whh,  const float* __restrict__ bhh,
    const float* __restrict__ dW1,  const float* __restrict__ db1,  const float* __restrict__ dW2,  const float* __restrict__ db2,
    char* __restrict__ ws)
{
    const int f = blockIdx.x, l = threadIdx.x;
    const int sg = l >> 4, c16 = l & 15;
    char* dst = ws + (size_t)f * 1024 + (size_t)l * 16;

    int kind = 0;                 // 0: bf16 weight frag, 1: f32 bias frag
    const float* W = nullptr; const float* B1 = nullptr; const float* B2 = nullptr;
    int t = 0, kb = 0, ncol = 64, coloff = 0, boff = 0, mlp = 0;
    bool msgmask = false, decw2 = false, db2frag = false;

    if (f < 108) {
        const int m = f / 36, r = f % 36;
        const float* W1 = (m == 0 ? pcW1 : (m == 1 ? fcW1 : ycW1));
        const float* W2 = (m == 0 ? pcW2 : (m == 1 ? fcW2 : ycW2));
        const float* b1 = (m == 0 ? pcb1 : (m == 1 ? fcb1 : ycb1));
        const float* b2 = (m == 0 ? pcb2 : (m == 1 ? fcb2 : ycb2));
        if (r < 20)      { W = W1; kb = r >> 2; t = r & 3; msgmask = (kb == 4); mlp = m; }
        else if (r < 28) { W = W2; int rr = r - 20; kb = rr >> 2; t = rr & 3; }
        else if (r < 32) { kind = 1; B1 = b1; t = r - 28; }
        else             { kind = 1; B1 = b2; t = r - 32; }
    } else if (f < 132) {
        const int r = f - 108;
        if (r < 8)       { W = ndW1; kb = r >> 2; t = r & 3; }
        else if (r < 16) { W = ndW2; int rr = r - 8; kb = rr >> 2; t = rr & 3; }
        else if (r < 20) { kind = 1; B1 = ndb1; t = r - 16; }
        else             { kind = 1; B1 = ndb2; t = r - 20; }
    } else if (f < 164) {
        const int r = f - 132; ncol = 192;
        if (r < 8)       { W = Whh; coloff = 128; kb = r >> 2; t = r & 3; }
        else if (r < 16) { W = Wih; coloff = 0;   int rr = r - 8;  kb = rr >> 2; t = rr & 3; }
        else if (r < 24) { W = Whh; coloff = 0;   int rr = r - 16; kb = rr >> 2; t = rr & 3; }
        else if (r < 28) { kind = 1; B1 = bhh; boff = 128; t = r - 24; }
        else             { kind = 1; B1 = bih; B2 = bhh; boff = 0; t = r - 28; }
    } else if (f < 196) {
        const int r = f - 164; ncol = 192;
        if (r < 8)       { W = Wih; coloff = 128; kb = r >> 2; t = r & 3; }
        else if (r < 16) { W = Wih; coloff = 64;  int rr = r - 8;  kb = rr >> 2; t = rr & 3; }
        else if (r < 24) { W = Whh; coloff = 64;  int rr = r - 16; kb = rr >> 2; t = rr & 3; }
        else if (r < 28) { kind = 1; B1 = bih; boff = 128; t = r - 24; }
        else             { kind = 1; B1 = bih; B2 = bhh; boff = 64; t = r - 28; }
    } else {
        const int r = f - 196;
        if (r < 8)       { W = dW1; kb = r >> 2; t = r & 3; }
        else if (r < 10) { W = dW2; kb = r - 8; t = 0; decw2 = true; }
        else if (r < 14) { kind = 1; B1 = db1; t = r - 10; }
        else             { kind = 1; B1 = db2; t = 0; db2frag = true; }
    }

    if (!kind) {
        const int row = 16 * t + c16;
        bf8v v;
        #pragma unroll
        for (int j = 0; j < 8; ++j) {
            const int k = kb * 32 + sg * 8 + j;
            float x;
            if (msgmask) { const int kk = k - 128 - mlp * 4; x = (kk >= 0 && kk < 4) ? W[(128 + kk) * 64 + row] : 0.f; }
            else if (decw2) { x = (row < 4) ? W[k * 4 + row] : 0.f; }
            else { x = W[k * ncol + coloff + row]; }
            v[j] = (__bf16)x;
        }
        *(bf8v*)dst = v;
    } else {
        f4 o;
        #pragma unroll
        for (int r4 = 0; r4 < 4; ++r4) {
            float x;
            if (db2frag) { x = (sg == 0 && t == 0) ? B1[r4] : 0.f; }
            else {
                const int fi = boff + 16 * t + 4 * sg + r4;
                x = B1[fi]; if (B2) x += B2[fi];
            }
            o[r4] = x;
        }
        *(f4*)dst = o;
    }
}

// ---------------- LDS layout (bytes) ----------------
#define WBUF 0             // 36 frags x 1KB, single-buffered per phase
#define HXT  36864         // 130 rows x 128B (pos n0-1 .. n0+128), swizzled
#define ACT  53504         // 128 rows x 128B (wave-private rows)
#define LDSZ 69888

__global__ __launch_bounds__(256, 2) void kgnn_main(
    const float* __restrict__ hx,  const float* __restrict__ pcm,
    const float* __restrict__ fcm, const float* __restrict__ ycm,
    const float* __restrict__ hy,
    const char*  __restrict__ ws,  float* __restrict__ out)
{
    __shared__ __align__(16) char LD[LDSZ];
    const int tid  = threadIdx.x;
    const int b    = blockIdx.x >> 5;
    const int tile = blockIdx.x & 31;
    const int n0   = tile * 128;
    const int baseH = b * 64 * NPOS;
    const int baseX = b * 4 * NPOS;

    const int lane = tid & 63, wid = tid >> 6;
    const int s = lane >> 4, q = lane & 15;
    const int Pv[2] = { wid * 32 + q, wid * 32 + 16 + q };

    // ---- hoisted direct global loads (issue early, far ahead of use) ----
    bf8v hyf[2][2], msgB[2];
    #pragma unroll
    for (int cc = 0; cc < 2; ++cc) {
        const int gn = n0 + Pv[cc];
        #pragma unroll
        for (int h = 0; h < 2; ++h)
            #pragma unroll
            for (int j = 0; j < 8; ++j)
                hyf[cc][h][j] = (__bf16)hy[baseH + (h * 32 + 8 * s + j) * NPOS + gn];
        #pragma unroll
        for (int j = 0; j < 8; ++j) {
            const int idx = 8 * s + j;
            float x = 0.f;
            if      (idx < 4)  x = pcm[baseX + idx * NPOS + gn];
            else if (idx < 8)  x = fcm[baseX + (idx - 4) * NPOS + gn];
            else if (idx < 12) x = ycm[baseX + (idx - 8) * NPOS + gn];
            msgB[cc][j] = (__bf16)x;
        }
    }

    // ---- weight-phase staging: wave-interleaved 16B copies ----
    auto stageW = [&](int gbase, int nf) {
        #pragma unroll
        for (int f0 = 0; f0 < 9; ++f0) {
            const int f = f0 * 4 + wid;
            if (f < nf) {
                f4 v = *(const f4*)(ws + ((size_t)(gbase + f) << 10) + ((size_t)lane << 4));
                *(f4*)(LD + WBUF + (f << 10) + (lane << 4)) = v;
            }
        }
    };

    // ---- hx staging -> HXT (4x reuse: n-1, n, n+1, hprev) ----
    #pragma unroll
    for (int it = 0; it < 8; ++it) {
        const int idx = it * 256 + tid;
        const int pp = idx & 127, fg = idx >> 7;
        const int gn = n0 + pp;
        bf4v h;
        #pragma unroll
        for (int j = 0; j < 4; ++j) h[j] = (__bf16)hx[baseH + (4 * fg + j) * NPOS + gn];
        const int row = pp + 1;
        *(bf4v*)(LD + HXT + row * 128 + ((8 * fg) ^ ((row & 7) << 4))) = h;
    }
    if (tid < 32) {
        const int side = tid & 1, fg = tid >> 1;
        const int row = side ? 129 : 0;
        const int gn = side ? min(n0 + 128, NPOS - 1) : max(n0 - 1, 0);
        bf4v h;
        #pragma unroll
        for (int j = 0; j < 4; ++j) h[j] = (__bf16)hx[baseH + (4 * fg + j) * NPOS + gn];
        *(bf4v*)(LD + HXT + row * 128 + ((8 * fg) ^ ((row & 7) << 4))) = h;
    }
    stageW(0, 36);                 // phase P0 weights
    __syncthreads();

    auto ldAL = [&](int fl) -> bf8v {
        return *(const bf8v*)(LD + WBUF + (fl << 10) + (lane << 4));
    };
    auto ldBiasL = [&](int fl) -> f4 {
        return *(const f4*)(LD + WBUF + (fl << 10) + (lane << 4));
    };
    auto ldB = [&](int base, int row, int h) -> bf8v {
        return *(const bf8v*)(LD + base + row * 128 + ((((h << 6) | (s << 4))) ^ ((row & 7) << 4)));
    };
    auto stAct = [&](int row, int t, f4 v, bool relu) {
        bf4v h;
        #pragma unroll
        for (int r = 0; r < 4; ++r) {
            float x = v[r]; if (relu) x = fmaxf(x, 0.f);
            h[r] = (__bf16)x;
        }
        *(bf4v*)(LD + ACT + row * 128 + (((t << 5) | (s << 3)) ^ ((row & 7) << 4))) = h;
    };

    bf8v hxn0[2], hxn1[2];
    #pragma unroll
    for (int cc = 0; cc < 2; ++cc) {
        hxn0[cc] = ldB(HXT, Pv[cc] + 1, 0);
        hxn1[cc] = ldB(HXT, Pv[cc] + 1, 1);
    }

    // ======== pc / fc / yc MLPs ========
    f4 sum3[2][4];
    #pragma unroll
    for (int m = 0; m < 3; ++m) {
        bf8v e0[2], e1[2];
        #pragma unroll
        for (int cc = 0; cc < 2; ++cc) {
            if (m == 0)      { e0[cc] = ldB(HXT, Pv[cc],     0); e1[cc] = ldB(HXT, Pv[cc],     1); }
            else if (m == 1) { e0[cc] = ldB(HXT, Pv[cc] + 2, 0); e1[cc] = ldB(HXT, Pv[cc] + 2, 1); }
            else             { e0[cc] = hyf[cc][0];              e1[cc] = hyf[cc][1]; }
        }
        f4 a[2][4];
        #pragma unroll
        for (int t = 0; t < 4; ++t) { f4 bv = ldBiasL(28 + t); a[0][t] = bv; a[1][t] = bv; }
        #pragma unroll
        for (int t = 0; t < 4; ++t) { bf8v A = ldAL(t);      a[0][t] = MF(A, e0[0],   a[0][t]); a[1][t] = MF(A, e0[1],   a[1][t]); }
        #pragma unroll
        for (int t = 0; t < 4; ++t) { bf8v A = ldAL(4 + t);  a[0][t] = MF(A, e1[0],   a[0][t]); a[1][t] = MF(A, e1[1],   a[1][t]); }
        #pragma unroll
        for (int t = 0; t < 4; ++t) { bf8v A = ldAL(8 + t);  a[0][t] = MF(A, hxn0[0], a[0][t]); a[1][t] = MF(A, hxn0[1], a[1][t]); }
        #pragma unroll
        for (int t = 0; t < 4; ++t) { bf8v A = ldAL(12 + t); a[0][t] = MF(A, hxn1[0], a[0][t]); a[1][t] = MF(A, hxn1[1], a[1][t]); }
        #pragma unroll
        for (int t = 0; t < 4; ++t) { bf8v A = ldAL(16 + t); a[0][t] = MF(A, msgB[0], a[0][t]); a[1][t] = MF(A, msgB[1], a[1][t]); }
        #pragma unroll
        for (int cc = 0; cc < 2; ++cc)
            #pragma unroll
            for (int t = 0; t < 4; ++t) stAct(Pv[cc], t, a[cc][t], true);

        bf8v c0[2] = { ldB(ACT, Pv[0], 0), ldB(ACT, Pv[1], 0) };
        bf8v c1[2] = { ldB(ACT, Pv[0], 1), ldB(ACT, Pv[1], 1) };
        f4 a2[2][4];
        #pragma unroll
        for (int t = 0; t < 4; ++t) { f4 bv = ldBiasL(32 + t); a2[0][t] = bv; a2[1][t] = bv; }
        #pragma unroll
        for (int t = 0; t < 4; ++t) { bf8v A = ldAL(20 + t); a2[0][t] = MF(A, c0[0], a2[0][t]); a2[1][t] = MF(A, c0[1], a2[1][t]); }
        #pragma unroll
        for (int t = 0; t < 4; ++t) { bf8v A = ldAL(24 + t); a2[0][t] = MF(A, c1[0], a2[0][t]); a2[1][t] = MF(A, c1[1], a2[1][t]); }
        #pragma unroll
        for (int cc = 0; cc < 2; ++cc)
            #pragma unroll
            for (int t = 0; t < 4; ++t)
                #pragma unroll
                for (int r = 0; r < 4; ++r) {
                    float x = fmaxf(a2[cc][t][r], 0.f);
                    if (m == 0) sum3[cc][t][r] = x; else sum3[cc][t][r] += x;
                }
        // stage next phase: P1 / P2 / P3(nd)
        __syncthreads();
        stageW(m == 0 ? 36 : (m == 1 ? 72 : 108), m == 2 ? 24 : 36);
        __syncthreads();
    }

    // ======== nd MLP -> U (both layers in P3 buffer) ========
    #pragma unroll
    for (int cc = 0; cc < 2; ++cc)
        #pragma unroll
        for (int t = 0; t < 4; ++t) stAct(Pv[cc], t, sum3[cc][t], false);
    #pragma unroll
    for (int L = 0; L < 2; ++L) {
        bf8v u0[2] = { ldB(ACT, Pv[0], 0), ldB(ACT, Pv[1], 0) };
        bf8v u1[2] = { ldB(ACT, Pv[0], 1), ldB(ACT, Pv[1], 1) };
        const int wb = L * 8, bi = 16 + L * 4;
        f4 a[2][4];
        #pragma unroll
        for (int t = 0; t < 4; ++t) { f4 bv = ldBiasL(bi + t); a[0][t] = bv; a[1][t] = bv; }
        #pragma unroll
        for (int t = 0; t < 4; ++t) { bf8v A = ldAL(wb + t);     a[0][t] = MF(A, u0[0], a[0][t]); a[1][t] = MF(A, u0[1], a[1][t]); }
        #pragma unroll
        for (int t = 0; t < 4; ++t) { bf8v A = ldAL(wb + 4 + t); a[0][t] = MF(A, u1[0], a[0][t]); a[1][t] = MF(A, u1[1], a[1][t]); }
        #pragma unroll
        for (int cc = 0; cc < 2; ++cc)
            #pragma unroll
            for (int t = 0; t < 4; ++t) stAct(Pv[cc], t, a[cc][t], true);
    }
    __syncthreads();
    stageW(132, 32);               // P4 GRU-A
    __syncthreads();

    // ======== GRU-A: hg, r, g = sigm(r)*hg ========
    f4 g[2][4];
    {
        bf8v uu0[2] = { ldB(ACT, Pv[0], 0), ldB(ACT, Pv[1], 0) };
        bf8v uu1[2] = { ldB(ACT, Pv[0], 1), ldB(ACT, Pv[1], 1) };
        bf8v hh0[2] = { ldB(HXT, Pv[0] + 1, 0), ldB(HXT, Pv[1] + 1, 0) };
        bf8v hh1[2] = { ldB(HXT, Pv[0] + 1, 1), ldB(HXT, Pv[1] + 1, 1) };
        #pragma unroll
        for (int t = 0; t < 4; ++t) { f4 bv = ldBiasL(24 + t); g[0][t] = bv; g[1][t] = bv; }
        #pragma unroll
        for (int t = 0; t < 4; ++t) { bf8v A = ldAL(t);     g[0][t] = MF(A, hh0[0], g[0][t]); g[1][t] = MF(A, hh0[1], g[1][t]); }
        #pragma unroll
        for (int t = 0; t < 4; ++t) { bf8v A = ldAL(4 + t); g[0][t] = MF(A, hh1[0], g[0][t]); g[1][t] = MF(A, hh1[1], g[1][t]); }
        f4 rr[2][4];
        #pragma unroll
        for (int t = 0; t < 4; ++t) { f4 bv = ldBiasL(28 + t); rr[0][t] = bv; rr[1][t] = bv; }
        #pragma unroll
        for (int t = 0; t < 4; ++t) { bf8v A = ldAL(8 + t);  rr[0][t] = MF(A, uu0[0], rr[0][t]); rr[1][t] = MF(A, uu0[1], rr[1][t]); }
        #pragma unroll
        for (int t = 0; t < 4; ++t) { bf8v A = ldAL(12 + t); rr[0][t] = MF(A, uu1[0], rr[0][t]); rr[1][t] = MF(A, uu1[1], rr[1][t]); }
        #pragma unroll
        for (int t = 0; t < 4; ++t) { bf8v A = ldAL(16 + t); rr[0][t] = MF(A, hh0[0], rr[0][t]); rr[1][t] = MF(A, hh0[1], rr[1][t]); }
        #pragma unroll
        for (int t = 0; t < 4; ++t) { bf8v A = ldAL(20 + t); rr[0][t] = MF(A, hh1[0], rr[0][t]); rr[1][t] = MF(A, hh1[1], rr[1][t]); }
        #pragma unroll
        for (int cc = 0; cc < 2; ++cc)
            #pragma unroll
            for (int t = 0; t < 4; ++t)
                #pragma unroll
                for (int r = 0; r < 4; ++r) g[cc][t][r] = sigm(rr[cc][t][r]) * g[cc][t][r];
    }
    __syncthreads();
    stageW(164, 32);               // P5 GRU-B
    __syncthreads();

    // ======== GRU-B: n = tanh(ig + g), z, hnew ========
    {
        bf8v uu0[2] = { ldB(ACT, Pv[0], 0), ldB(ACT, Pv[1], 0) };
        bf8v uu1[2] = { ldB(ACT, Pv[0], 1), ldB(ACT, Pv[1], 1) };
        bf8v hh0[2] = { ldB(HXT, Pv[0] + 1, 0), ldB(HXT, Pv[1] + 1, 0) };
        bf8v hh1[2] = { ldB(HXT, Pv[0] + 1, 1), ldB(HXT, Pv[1] + 1, 1) };
        f4 gi[2][4];
        #pragma unroll
        for (int t = 0; t < 4; ++t) { f4 bv = ldBiasL(24 + t); gi[0][t] = bv; gi[1][t] = bv; }
        #pragma unroll
        for (int t = 0; t < 4; ++t) { bf8v A = ldAL(t);     gi[0][t] = MF(A, uu0[0], gi[0][t]); gi[1][t] = MF(A, uu0[1], gi[1][t]); }
        #pragma unroll
        for (int t = 0; t < 4; ++t) { bf8v A = ldAL(4 + t); gi[0][t] = MF(A, uu1[0], gi[0][t]); gi[1][t] = MF(A, uu1[1], gi[1][t]); }
        #pragma unroll
        for (int cc = 0; cc < 2; ++cc)
            #pragma unroll
            for (int t = 0; t < 4; ++t)
                #pragma unroll
                for (int r = 0; r < 4; ++r) g[cc][t][r] = tanh_f(gi[cc][t][r] + g[cc][t][r]);
        f4 zz[2][4];
        #pragma unroll
        for (int t = 0; t < 4; ++t) { f4 bv = ldBiasL(28 + t); zz[0][t] = bv; zz[1][t] = bv; }
        #pragma unroll
        for (int t = 0; t < 4; ++t) { bf8v A = ldAL(8 + t);  zz[0][t] = MF(A, uu0[0], zz[0][t]); zz[1][t] = MF(A, uu0[1], zz[1][t]); }
        #pragma unroll
        for (int t = 0; t < 4; ++t) { bf8v A = ldAL(12 + t); zz[0][t] = MF(A, uu1[0], zz[0][t]); zz[1][t] = MF(A, uu1[1], zz[1][t]); }
        #pragma unroll
        for (int t = 0; t < 4; ++t) { bf8v A = ldAL(16 + t); zz[0][t] = MF(A, hh0[0], zz[0][t]); zz[1][t] = MF(A, hh0[1], zz[1][t]); }
        #pragma unroll
        for (int t = 0; t < 4; ++t) { bf8v A = ldAL(20 + t); zz[0][t] = MF(A, hh1[0], zz[0][t]); zz[1][t] = MF(A, hh1[1], zz[1][t]); }

        float* __restrict__ outH = out + NB * 4 * NPOS + baseH;
        #pragma unroll
        for (int cc = 0; cc < 2; ++cc) {
            const int hrow = Pv[cc] + 1;
            const int gn = n0 + Pv[cc];
            #pragma unroll
            for (int t = 0; t < 4; ++t) {
                bf4v hp4 = *(const bf4v*)(LD + HXT + hrow * 128 +
                                          (((t << 5) | (s << 3)) ^ ((hrow & 7) << 4)));
                bf4v hnb;
                #pragma unroll
                for (int r = 0; r < 4; ++r) {
                    float z  = sigm(zz[cc][t][r]);
                    float nn = g[cc][t][r];
                    float hp = (float)hp4[r];
                    float hn = nn + z * (hp - nn);
                    outH[(16 * t + 4 * s + r) * NPOS + gn] = hn;
                    hnb[r] = (__bf16)hn;
                }
                *(bf4v*)(LD + ACT + Pv[cc] * 128 + (((t << 5) | (s << 3)) ^ ((Pv[cc] & 7) << 4))) = hnb;
            }
        }
    }
    __syncthreads();
    stageW(196, 15);               // P6 dec
    __syncthreads();

    // ======== decoder ========
    {
        bf8v d0[2] = { ldB(ACT, Pv[0], 0), ldB(ACT, Pv[1], 0) };
        bf8v d1[2] = { ldB(ACT, Pv[0], 1), ldB(ACT, Pv[1], 1) };
        f4 a[2][4];
        #pragma unroll
        for (int t = 0; t < 4; ++t) { f4 bv = ldBiasL(10 + t); a[0][t] = bv; a[1][t] = bv; }
        #pragma unroll
        for (int t = 0; t < 4; ++t) { bf8v A = ldAL(t);     a[0][t] = MF(A, d0[0], a[0][t]); a[1][t] = MF(A, d0[1], a[1][t]); }
        #pragma unroll
        for (int t = 0; t < 4; ++t) { bf8v A = ldAL(4 + t); a[0][t] = MF(A, d1[0], a[0][t]); a[1][t] = MF(A, d1[1], a[1][t]); }
        #pragma unroll
        for (int cc = 0; cc < 2; ++cc)
            #pragma unroll
            for (int t = 0; t < 4; ++t) stAct(Pv[cc], t, a[cc][t], true);

        bf8v e0[2] = { ldB(ACT, Pv[0], 0), ldB(ACT, Pv[1], 0) };
        bf8v e1[2] = { ldB(ACT, Pv[0], 1), ldB(ACT, Pv[1], 1) };
        f4 ep[2];
        { f4 bv = ldBiasL(14); ep[0] = bv; ep[1] = bv; }
        { bf8v A = ldAL(8); ep[0] = MF(A, e0[0], ep[0]); ep[1] = MF(A, e0[1], ep[1]); }
        { bf8v A = ldAL(9); ep[0] = MF(A, e1[0], ep[0]); ep[1] = MF(A, e1[1], ep[1]); }
        if (s == 0) {
            #pragma unroll
            for (int cc = 0; cc < 2; ++cc) {
                const int gn = n0 + Pv[cc];
                #pragma unroll
                for (int r = 0; r < 4; ++r) out[baseX + r * NPOS + gn] = ep[cc][r];
            }
        }
    }
}

extern "C" void kernel_launch(void* const* d_in, const int* in_sizes, int n_in,
                              void* d_out, int out_size, void* d_ws, size_t ws_size,
                              hipStream_t stream) {
    const float* hx   = (const float*)d_in[0];
    const float* pcm  = (const float*)d_in[1];
    const float* fcm  = (const float*)d_in[2];
    const float* ycm  = (const float*)d_in[3];
    const float* hy   = (const float*)d_in[4];

    prep_kernel<<<dim3(NFRAG), dim3(64), 0, stream>>>(
        (const float*)d_in[5],  (const float*)d_in[6],  (const float*)d_in[7],  (const float*)d_in[8],
        (const float*)d_in[9],  (const float*)d_in[10], (const float*)d_in[11], (const float*)d_in[12],
        (const float*)d_in[13], (const float*)d_in[14], (const float*)d_in[15], (const float*)d_in[16],
        (const float*)d_in[17], (const float*)d_in[18], (const float*)d_in[19], (const float*)d_in[20],
        (const float*)d_in[21], (const float*)d_in[22], (const float*)d_in[23], (const float*)d_in[24],
        (const float*)d_in[25], (const float*)d_in[26], (const float*)d_in[27], (const float*)d_in[28],
        (char*)d_ws);

    kgnn_main<<<dim3(NB * 32), dim3(256), 0, stream>>>(
        hx, pcm, fcm, ycm, hy, (const char*)d_ws, (float*)d_out);
}

// Round 8
// 115.892 us; speedup vs baseline: 1.6207x; 1.0139x over previous
//
#include <hip/hip_runtime.h>

#define NPOS 4096
#define NB   64

typedef __bf16 bf8v __attribute__((ext_vector_type(8)));
typedef __bf16 bf4v __attribute__((ext_vector_type(4)));
typedef float  f4   __attribute__((ext_vector_type(4)));

__device__ __forceinline__ float sigm(float x)   { return 1.0f / (1.0f + __expf(-x)); }
__device__ __forceinline__ float tanh_f(float x) { return 1.0f - 2.0f / (1.0f + __expf(2.0f * x)); }

__device__ __forceinline__ f4 MF(bf8v a, bf8v b, f4 c) {
    return __builtin_amdgcn_mfma_f32_16x16x32_bf16(a, b, c, 0, 0, 0);
}

// ---------------- phase-contiguous frag layout in d_ws (1KB frags) ----------------
// P0/P1/P2 (pc/fc/yc) base m*36:
//   +0..19  W1 [kb*4+t] kb=0..4 (kb4 = message block, per-mlp masked)
//   +20..27 W2 [kb*4+t] kb=0..1
//   +28..31 b1[t]   +32..35 b2[t]
// P3 (nd) base 108: +0..7 ndW1, +8..15 ndW2, +16..19 ndb1, +20..23 ndb2
// P4 (GRU-A) base 132: +0..7 Whh[:,128:] (hg), +8..15 Wih[:,0:64] (r),
//   +16..23 Whh[:,0:64] (r), +24..27 bHG, +28..31 bR(=bih+bhh [0:64])
// P5 (GRU-B) base 164: +0..7 Wih[:,128:] (ig), +8..15 Wih[:,64:128] (z),
//   +16..23 Whh[:,64:128] (z), +24..27 bIG, +28..31 bZ(=bih+bhh [64:128])
// P6 (dec) base 196: +0..7 dW1, +8..9 dW2, +10..13 db1, +14 db2
#define NFRAG 211

__global__ __launch_bounds__(64) void prep_kernel(
    const float* __restrict__ pcW1, const float* __restrict__ pcb1, const float* __restrict__ pcW2, const float* __restrict__ pcb2,
    const float* __restrict__ fcW1, const float* __restrict__ fcb1, const float* __restrict__ fcW2, const float* __restrict__ fcb2,
    const float* __restrict__ ycW1, const float* __restrict__ ycb1, const float* __restrict__ ycW2, const float* __restrict__ ycb2,
    const float* __restrict__ ndW1, const float* __restrict__ ndb1, const float* __restrict__ ndW2, const float* __restrict__ ndb2,
    const float* __restrict__ Wih,  const float* __restrict__ bih,  const float* __restrict__ Whh,  const float* __restrict__ bhh,
    const float* __restrict__ dW1,  const float* __restrict__ db1,  const float* __restrict__ dW2,  const float* __restrict__ db2,
    char* __restrict__ ws)
{
    const int f = blockIdx.x, l = threadIdx.x;
    const int sg = l >> 4, c16 = l & 15;
    char* dst = ws + (size_t)f * 1024 + (size_t)l * 16;

    int kind = 0;                 // 0: bf16 weight frag, 1: f32 bias frag
    const float* W = nullptr; const float* B1 = nullptr; const float* B2 = nullptr;
    int t = 0, kb = 0, ncol = 64, coloff = 0, boff = 0, mlp = 0;
    bool msgmask = false, decw2 = false, db2frag = false;

    if (f < 108) {
        const int m = f / 36, r = f % 36;
        const float* W1 = (m == 0 ? pcW1 : (m == 1 ? fcW1 : ycW1));
        const float* W2 = (m == 0 ? pcW2 : (m == 1 ? fcW2 : ycW2));
        const float* b1 = (m == 0 ? pcb1 : (m == 1 ? fcb1 : ycb1));
        const float* b2 = (m == 0 ? pcb2 : (m == 1 ? fcb2 : ycb2));
        if (r < 20)      { W = W1; kb = r >> 2; t = r & 3; msgmask = (kb == 4); mlp = m; }
        else if (r < 28) { W = W2; int rr = r - 20; kb = rr >> 2; t = rr & 3; }
        else if (r < 32) { kind = 1; B1 = b1; t = r - 28; }
        else             { kind = 1; B1 = b2; t = r - 32; }
    } else if (f < 132) {
        const int r = f - 108;
        if (r < 8)       { W = ndW1; kb = r >> 2; t = r & 3; }
        else if (r < 16) { W = ndW2; int rr = r - 8; kb = rr >> 2; t = rr & 3; }
        else if (r < 20) { kind = 1; B1 = ndb1; t = r - 16; }
        else             { kind = 1; B1 = ndb2; t = r - 20; }
    } else if (f < 164) {
        const int r = f - 132; ncol = 192;
        if (r < 8)       { W = Whh; coloff = 128; kb = r >> 2; t = r & 3; }
        else if (r < 16) { W = Wih; coloff = 0;   int rr = r - 8;  kb = rr >> 2; t = rr & 3; }
        else if (r < 24) { W = Whh; coloff = 0;   int rr = r - 16; kb = rr >> 2; t = rr & 3; }
        else if (r < 28) { kind = 1; B1 = bhh; boff = 128; t = r - 24; }
        else             { kind = 1; B1 = bih; B2 = bhh; boff = 0; t = r - 28; }
    } else if (f < 196) {
        const int r = f - 164; ncol = 192;
        if (r < 8)       { W = Wih; coloff = 128; kb = r >> 2; t = r & 3; }
        else if (r < 16) { W = Wih; coloff = 64;  int rr = r - 8;  kb = rr >> 2; t = rr & 3; }
        else if (r < 24) { W = Whh; coloff = 64;  int rr = r - 16; kb = rr >> 2; t = rr & 3; }
        else if (r < 28) { kind = 1; B1 = bih; boff = 128; t = r - 24; }
        else             { kind = 1; B1 = bih; B2 = bhh; boff = 64; t = r - 28; }
    } else {
        const int r = f - 196;
        if (r < 8)       { W = dW1; kb = r >> 2; t = r & 3; }
        else if (r < 10) { W = dW2; kb = r - 8; t = 0; decw2 = true; }
        else if (r < 14) { kind = 1; B1 = db1; t = r - 10; }
        else             { kind = 1; B1 = db2; t = 0; db2frag = true; }
    }

    if (!kind) {
        const int row = 16 * t + c16;
        bf8v v;
        #pragma unroll
        for (int j = 0; j < 8; ++j) {
            const int k = kb * 32 + sg * 8 + j;
            float x;
            if (msgmask) { const int kk = k - 128 - mlp * 4; x = (kk >= 0 && kk < 4) ? W[(128 + kk) * 64 + row] : 0.f; }
            else if (decw2) { x = (row < 4) ? W[k * 4 + row] : 0.f; }
            else { x = W[k * ncol + coloff + row]; }
            v[j] = (__bf16)x;
        }
        *(bf8v*)dst = v;
    } else {
        f4 o;
        #pragma unroll
        for (int r4 = 0; r4 < 4; ++r4) {
            float x;
            if (db2frag) { x = (sg == 0 && t == 0) ? B1[r4] : 0.f; }
            else {
                const int fi = boff + 16 * t + 4 * sg + r4;
                x = B1[fi]; if (B2) x += B2[fi];
            }
            o[r4] = x;
        }
        *(f4*)dst = o;
    }
}

// ---------------- LDS layout (bytes) ----------------
#define WBUF 0             // 36 frags x 1KB, single-buffered per phase
#define ACT  36864         // 128 rows x 128B (wave-private rows)
#define LDSZ 53248         // 163840/53248 = 3 blocks/CU

__global__ __launch_bounds__(256, 2) void kgnn_main(
    const float* __restrict__ hx,  const float* __restrict__ pcm,
    const float* __restrict__ fcm, const float* __restrict__ ycm,
    const float* __restrict__ hy,
    const char*  __restrict__ ws,  float* __restrict__ out)
{
    __shared__ __align__(16) char LD[LDSZ];
    const int tid  = threadIdx.x;
    const int b    = blockIdx.x >> 5;
    const int tile = blockIdx.x & 31;
    const int n0   = tile * 128;
    const int baseH = b * 64 * NPOS;
    const int baseX = b * 4 * NPOS;

    const int lane = tid & 63, wid = tid >> 6;
    const int s = lane >> 4, q = lane & 15;
    const int Pv[2] = { wid * 32 + q, wid * 32 + 16 + q };
    const int Gn[2] = { n0 + Pv[0], n0 + Pv[1] };

    // B-frag loader from a position-strided [64][NPOS] f32 tensor (feats h*32+8s..+7)
    auto ldTB = [&](const float* __restrict__ T, int gnq, int h) -> bf8v {
        bf8v v;
        #pragma unroll
        for (int j = 0; j < 8; ++j)
            v[j] = (__bf16)T[baseH + (h * 32 + 8 * s + j) * NPOS + gnq];
        return v;
    };

    // ---- hoisted: hx[n] B-frags (reused by all 3 MLPs and GRU) + message B-frags ----
    bf8v hxn0[2], hxn1[2], msgB[2];
    #pragma unroll
    for (int cc = 0; cc < 2; ++cc) {
        hxn0[cc] = ldTB(hx, Gn[cc], 0);
        hxn1[cc] = ldTB(hx, Gn[cc], 1);
        #pragma unroll
        for (int j = 0; j < 8; ++j) {
            const int idx = 8 * s + j;
            float x = 0.f;
            if      (idx < 4)  x = pcm[baseX + idx * NPOS + Gn[cc]];
            else if (idx < 8)  x = fcm[baseX + (idx - 4) * NPOS + Gn[cc]];
            else if (idx < 12) x = ycm[baseX + (idx - 8) * NPOS + Gn[cc]];
            msgB[cc][j] = (__bf16)x;
        }
    }

    // ---- weight-phase staging: wave-interleaved 16B copies ----
    auto stageW = [&](int gbase, int nf) {
        #pragma unroll
        for (int f0 = 0; f0 < 9; ++f0) {
            const int f = f0 * 4 + wid;
            if (f < nf) {
                f4 v = *(const f4*)(ws + ((size_t)(gbase + f) << 10) + ((size_t)lane << 4));
                *(f4*)(LD + WBUF + (f << 10) + (lane << 4)) = v;
            }
        }
    };

    stageW(0, 36);                 // phase P0 weights
    __syncthreads();

    auto ldAL = [&](int fl) -> bf8v {
        return *(const bf8v*)(LD + WBUF + (fl << 10) + (lane << 4));
    };
    auto ldBiasL = [&](int fl) -> f4 {
        return *(const f4*)(LD + WBUF + (fl << 10) + (lane << 4));
    };
    auto ldACT = [&](int row, int h) -> bf8v {
        return *(const bf8v*)(LD + ACT + row * 128 + ((((h << 6) | (s << 4))) ^ ((row & 7) << 4)));
    };
    auto stAct = [&](int row, int t, f4 v, bool relu) {
        bf4v h;
        #pragma unroll
        for (int r = 0; r < 4; ++r) {
            float x = v[r]; if (relu) x = fmaxf(x, 0.f);
            h[r] = (__bf16)x;
        }
        *(bf4v*)(LD + ACT + row * 128 + (((t << 5) | (s << 3)) ^ ((row & 7) << 4))) = h;
    };

    // ======== pc / fc / yc MLPs ========
    f4 sum3[2][4];
    #pragma unroll
    for (int m = 0; m < 3; ++m) {
        bf8v e0[2], e1[2];
        #pragma unroll
        for (int cc = 0; cc < 2; ++cc) {
            if (m == 0) {
                const int gm = (Gn[cc] == 0) ? 0 : Gn[cc] - 1;
                e0[cc] = ldTB(hx, gm, 0); e1[cc] = ldTB(hx, gm, 1);
            } else if (m == 1) {
                const int gp = (Gn[cc] == NPOS - 1) ? NPOS - 1 : Gn[cc] + 1;
                e0[cc] = ldTB(hx, gp, 0); e1[cc] = ldTB(hx, gp, 1);
            } else {
                e0[cc] = ldTB(hy, Gn[cc], 0); e1[cc] = ldTB(hy, Gn[cc], 1);
            }
        }
        f4 a[2][4];
        #pragma unroll
        for (int t = 0; t < 4; ++t) { f4 bv = ldBiasL(28 + t); a[0][t] = bv; a[1][t] = bv; }
        #pragma unroll
        for (int t = 0; t < 4; ++t) { bf8v A = ldAL(t);      a[0][t] = MF(A, e0[0],   a[0][t]); a[1][t] = MF(A, e0[1],   a[1][t]); }
        #pragma unroll
        for (int t = 0; t < 4; ++t) { bf8v A = ldAL(4 + t);  a[0][t] = MF(A, e1[0],   a[0][t]); a[1][t] = MF(A, e1[1],   a[1][t]); }
        #pragma unroll
        for (int t = 0; t < 4; ++t) { bf8v A = ldAL(8 + t);  a[0][t] = MF(A, hxn0[0], a[0][t]); a[1][t] = MF(A, hxn0[1], a[1][t]); }
        #pragma unroll
        for (int t = 0; t < 4; ++t) { bf8v A = ldAL(12 + t); a[0][t] = MF(A, hxn1[0], a[0][t]); a[1][t] = MF(A, hxn1[1], a[1][t]); }
        #pragma unroll
        for (int t = 0; t < 4; ++t) { bf8v A = ldAL(16 + t); a[0][t] = MF(A, msgB[0], a[0][t]); a[1][t] = MF(A, msgB[1], a[1][t]); }
        #pragma unroll
        for (int cc = 0; cc < 2; ++cc)
            #pragma unroll
            for (int t = 0; t < 4; ++t) stAct(Pv[cc], t, a[cc][t], true);

        bf8v c0[2] = { ldACT(Pv[0], 0), ldACT(Pv[1], 0) };
        bf8v c1[2] = { ldACT(Pv[0], 1), ldACT(Pv[1], 1) };
        f4 a2[2][4];
        #pragma unroll
        for (int t = 0; t < 4; ++t) { f4 bv = ldBiasL(32 + t); a2[0][t] = bv; a2[1][t] = bv; }
        #pragma unroll
        for (int t = 0; t < 4; ++t) { bf8v A = ldAL(20 + t); a2[0][t] = MF(A, c0[0], a2[0][t]); a2[1][t] = MF(A, c0[1], a2[1][t]); }
        #pragma unroll
        for (int t = 0; t < 4; ++t) { bf8v A = ldAL(24 + t); a2[0][t] = MF(A, c1[0], a2[0][t]); a2[1][t] = MF(A, c1[1], a2[1][t]); }
        #pragma unroll
        for (int cc = 0; cc < 2; ++cc)
            #pragma unroll
            for (int t = 0; t < 4; ++t)
                #pragma unroll
                for (int r = 0; r < 4; ++r) {
                    float x = fmaxf(a2[cc][t][r], 0.f);
                    if (m == 0) sum3[cc][t][r] = x; else sum3[cc][t][r] += x;
                }
        // stage next phase: P1 / P2 / P3(nd)
        __syncthreads();
        stageW(m == 0 ? 36 : (m == 1 ? 72 : 108), m == 2 ? 24 : 36);
        __syncthreads();
    }

    // ======== nd MLP -> U (both layers in P3 buffer) ========
    #pragma unroll
    for (int cc = 0; cc < 2; ++cc)
        #pragma unroll
        for (int t = 0; t < 4; ++t) stAct(Pv[cc], t, sum3[cc][t], false);
    #pragma unroll
    for (int L = 0; L < 2; ++L) {
        bf8v u0[2] = { ldACT(Pv[0], 0), ldACT(Pv[1], 0) };
        bf8v u1[2] = { ldACT(Pv[0], 1), ldACT(Pv[1], 1) };
        const int wb = L * 8, bi = 16 + L * 4;
        f4 a[2][4];
        #pragma unroll
        for (int t = 0; t < 4; ++t) { f4 bv = ldBiasL(bi + t); a[0][t] = bv; a[1][t] = bv; }
        #pragma unroll
        for (int t = 0; t < 4; ++t) { bf8v A = ldAL(wb + t);     a[0][t] = MF(A, u0[0], a[0][t]); a[1][t] = MF(A, u0[1], a[1][t]); }
        #pragma unroll
        for (int t = 0; t < 4; ++t) { bf8v A = ldAL(wb + 4 + t); a[0][t] = MF(A, u1[0], a[0][t]); a[1][t] = MF(A, u1[1], a[1][t]); }
        #pragma unroll
        for (int cc = 0; cc < 2; ++cc)
            #pragma unroll
            for (int t = 0; t < 4; ++t) stAct(Pv[cc], t, a[cc][t], true);
    }
    __syncthreads();
    stageW(132, 32);               // P4 GRU-A
    __syncthreads();

    // ======== GRU-A: hg, r, g = sigm(r)*hg ========
    f4 g[2][4];
    {
        bf8v uu0[2] = { ldACT(Pv[0], 0), ldACT(Pv[1], 0) };
        bf8v uu1[2] = { ldACT(Pv[0], 1), ldACT(Pv[1], 1) };
        #pragma unroll
        for (int t = 0; t < 4; ++t) { f4 bv = ldBiasL(24 + t); g[0][t] = bv; g[1][t] = bv; }
        #pragma unroll
        for (int t = 0; t < 4; ++t) { bf8v A = ldAL(t);     g[0][t] = MF(A, hxn0[0], g[0][t]); g[1][t] = MF(A, hxn0[1], g[1][t]); }
        #pragma unroll
        for (int t = 0; t < 4; ++t) { bf8v A = ldAL(4 + t); g[0][t] = MF(A, hxn1[0], g[0][t]); g[1][t] = MF(A, hxn1[1], g[1][t]); }
        f4 rr[2][4];
        #pragma unroll
        for (int t = 0; t < 4; ++t) { f4 bv = ldBiasL(28 + t); rr[0][t] = bv; rr[1][t] = bv; }
        #pragma unroll
        for (int t = 0; t < 4; ++t) { bf8v A = ldAL(8 + t);  rr[0][t] = MF(A, uu0[0], rr[0][t]); rr[1][t] = MF(A, uu0[1], rr[1][t]); }
        #pragma unroll
        for (int t = 0; t < 4; ++t) { bf8v A = ldAL(12 + t); rr[0][t] = MF(A, uu1[0], rr[0][t]); rr[1][t] = MF(A, uu1[1], rr[1][t]); }
        #pragma unroll
        for (int t = 0; t < 4; ++t) { bf8v A = ldAL(16 + t); rr[0][t] = MF(A, hxn0[0], rr[0][t]); rr[1][t] = MF(A, hxn0[1], rr[1][t]); }
        #pragma unroll
        for (int t = 0; t < 4; ++t) { bf8v A = ldAL(20 + t); rr[0][t] = MF(A, hxn1[0], rr[0][t]); rr[1][t] = MF(A, hxn1[1], rr[1][t]); }
        #pragma unroll
        for (int cc = 0; cc < 2; ++cc)
            #pragma unroll
            for (int t = 0; t < 4; ++t)
                #pragma unroll
                for (int r = 0; r < 4; ++r) g[cc][t][r] = sigm(rr[cc][t][r]) * g[cc][t][r];
    }
    __syncthreads();
    stageW(164, 32);               // P5 GRU-B
    __syncthreads();

    // ======== GRU-B: n = tanh(ig + g), z, hnew ========
    {
        // hprev in C-layout, f32 direct (same pattern as outH store; issue early)
        f4 hpv[2][4];
        #pragma unroll
        for (int cc = 0; cc < 2; ++cc)
            #pragma unroll
            for (int t = 0; t < 4; ++t)
                #pragma unroll
                for (int r = 0; r < 4; ++r)
                    hpv[cc][t][r] = hx[baseH + (16 * t + 4 * s + r) * NPOS + Gn[cc]];

        bf8v uu0[2] = { ldACT(Pv[0], 0), ldACT(Pv[1], 0) };
        bf8v uu1[2] = { ldACT(Pv[0], 1), ldACT(Pv[1], 1) };
        f4 gi[2][4];
        #pragma unroll
        for (int t = 0; t < 4; ++t) { f4 bv = ldBiasL(24 + t); gi[0][t] = bv; gi[1][t] = bv; }
        #pragma unroll
        for (int t = 0; t < 4; ++t) { bf8v A = ldAL(t);     gi[0][t] = MF(A, uu0[0], gi[0][t]); gi[1][t] = MF(A, uu0[1], gi[1][t]); }
        #pragma unroll
        for (int t = 0; t < 4; ++t) { bf8v A = ldAL(4 + t); gi[0][t] = MF(A, uu1[0], gi[0][t]); gi[1][t] = MF(A, uu1[1], gi[1][t]); }
        #pragma unroll
        for (int cc = 0; cc < 2; ++cc)
            #pragma unroll
            for (int t = 0; t < 4; ++t)
                #pragma unroll
                for (int r = 0; r < 4; ++r) g[cc][t][r] = tanh_f(gi[cc][t][r] + g[cc][t][r]);
        f4 zz[2][4];
        #pragma unroll
        for (int t = 0; t < 4; ++t) { f4 bv = ldBiasL(28 + t); zz[0][t] = bv; zz[1][t] = bv; }
        #pragma unroll
        for (int t = 0; t < 4; ++t) { bf8v A = ldAL(8 + t);  zz[0][t] = MF(A, uu0[0], zz[0][t]); zz[1][t] = MF(A, uu0[1], zz[1][t]); }
        #pragma unroll
        for (int t = 0; t < 4; ++t) { bf8v A = ldAL(12 + t); zz[0][t] = MF(A, uu1[0], zz[0][t]); zz[1][t] = MF(A, uu1[1], zz[1][t]); }
        #pragma unroll
        for (int t = 0; t < 4; ++t) { bf8v A = ldAL(16 + t); zz[0][t] = MF(A, hxn0[0], zz[0][t]); zz[1][t] = MF(A, hxn0[1], zz[1][t]); }
        #pragma unroll
        for (int t = 0; t < 4; ++t) { bf8v A = ldAL(20 + t); zz[0][t] = MF(A, hxn1[0], zz[0][t]); zz[1][t] = MF(A, hxn1[1], zz[1][t]); }

        float* __restrict__ outH = out + NB * 4 * NPOS + baseH;
        #pragma unroll
        for (int cc = 0; cc < 2; ++cc) {
            const int gn = Gn[cc];
            #pragma unroll
            for (int t = 0; t < 4; ++t) {
                bf4v hnb;
                #pragma unroll
                for (int r = 0; r < 4; ++r) {
                    float z  = sigm(zz[cc][t][r]);
                    float nn = g[cc][t][r];
                    float hp = hpv[cc][t][r];
                    float hn = nn + z * (hp - nn);
                    outH[(16 * t + 4 * s + r) * NPOS + gn] = hn;
                    hnb[r] = (__bf16)hn;
                }
                *(bf4v*)(LD + ACT + Pv[cc] * 128 + (((t << 5) | (s << 3)) ^ ((Pv[cc] & 7) << 4))) = hnb;
            }
        }
    }
    __syncthreads();
    stageW(196, 15);               // P6 dec
    __syncthreads();

    // ======== decoder ========
    {
        bf8v d0[2] = { ldACT(Pv[0], 0), ldACT(Pv[1], 0) };
        bf8v d1[2] = { ldACT(Pv[0], 1), ldACT(Pv[1], 1) };
        f4 a[2][4];
        #pragma unroll
        for (int t = 0; t < 4; ++t) { f4 bv = ldBiasL(10 + t); a[0][t] = bv; a[1][t] = bv; }
        #pragma unroll
        for (int t = 0; t < 4; ++t) { bf8v A = ldAL(t);     a[0][t] = MF(A, d0[0], a[0][t]); a[1][t] = MF(A, d0[1], a[1][t]); }
        #pragma unroll
        for (int t = 0; t < 4; ++t) { bf8v A = ldAL(4 + t); a[0][t] = MF(A, d1[0], a[0][t]); a[1][t] = MF(A, d1[1], a[1][t]); }
        #pragma unroll
        for (int cc = 0; cc < 2; ++cc)
            #pragma unroll
            for (int t = 0; t < 4; ++t) stAct(Pv[cc], t, a[cc][t], true);

        bf8v e0[2] = { ldACT(Pv[0], 0), ldACT(Pv[1], 0) };
        bf8v e1[2] = { ldACT(Pv[0], 1), ldACT(Pv[1], 1) };
        f4 ep[2];
        { f4 bv = ldBiasL(14); ep[0] = bv; ep[1] = bv; }
        { bf8v A = ldAL(8); ep[0] = MF(A, e0[0], ep[0]); ep[1] = MF(A, e0[1], ep[1]); }
        { bf8v A = ldAL(9); ep[0] = MF(A, e1[0], ep[0]); ep[1] = MF(A, e1[1], ep[1]); }
        if (s == 0) {
            #pragma unroll
            for (int cc = 0; cc < 2; ++cc) {
                #pragma unroll
                for (int r = 0; r < 4; ++r) out[baseX + r * NPOS + Gn[cc]] = ep[cc][r];
            }
        }
    }
}

extern "C" void kernel_launch(void* const* d_in, const int* in_sizes, int n_in,
                              void* d_out, int out_size, void* d_ws, size_t ws_size,
                              hipStream_t stream) {
    const float* hx   = (const float*)d_in[0];
    const float* pcm  = (const float*)d_in[1];
    const float* fcm  = (const float*)d_in[2];
    const float* ycm  = (const float*)d_in[3];
    const float* hy   = (const float*)d_in[4];

    prep_kernel<<<dim3(NFRAG), dim3(64), 0, stream>>>(
        (const float*)d_in[5],  (const float*)d_in[6],  (const float*)d_in[7],  (const float*)d_in[8],
        (const float*)d_in[9],  (const float*)d_in[10], (const float*)d_in[11], (const float*)d_in[12],
        (const float*)d_in[13], (const float*)d_in[14], (const float*)d_in[15], (const float*)d_in[16],
        (const float*)d_in[17], (const float*)d_in[18], (const float*)d_in[19], (const float*)d_in[20],
        (const float*)d_in[21], (const float*)d_in[22], (const float*)d_in[23], (const float*)d_in[24],
        (const float*)d_in[25], (const float*)d_in[26], (const float*)d_in[27], (const float*)d_in[28],
        (char*)d_ws);

    kgnn_main<<<dim3(NB * 32), dim3(256), 0, stream>>>(
        hx, pcm, fcm, ycm, hy, (const char*)d_ws, (float*)d_out);
}

// Round 9
// 111.019 us; speedup vs baseline: 1.6918x; 1.0439x over previous
//
#include <hip/hip_runtime.h>

#define NPOS 4096
#define NB   64

typedef __bf16 bf8v __attribute__((ext_vector_type(8)));
typedef float  f4   __attribute__((ext_vector_type(4)));

__device__ __forceinline__ float sigm(float x)   { return 1.0f / (1.0f + __expf(-x)); }
__device__ __forceinline__ float tanh_f(float x) { return 1.0f - 2.0f / (1.0f + __expf(2.0f * x)); }

__device__ __forceinline__ f4 MF(bf8v a, bf8v b, f4 c) {
    return __builtin_amdgcn_mfma_f32_16x16x32_bf16(a, b, c, 0, 0, 0);
}

// ---------------- phase-contiguous frag layout in d_ws (1KB frags) ----------------
// P0/P1/P2 (pc/fc/yc) base m*36:
//   +0..19  W1 [kb*4+t] kb=0..4 (kb4 = message block, per-mlp masked)   [natural]
//   +20..27 W2 [kb*4+t] kb=0..1                                         [PERM]
//   +28..31 b1[t]   +32..35 b2[t]
// P3 (nd) base 108: +0..7 ndW1 [PERM], +8..15 ndW2 [PERM], +16..19 ndb1, +20..23 ndb2
// P4 (GRU-A) base 132: +0..7 Whh[:,128:] (hg) [nat], +8..15 Wih[:,0:64] (r) [PERM],
//   +16..23 Whh[:,0:64] (r) [nat], +24..27 bHG, +28..31 bR
// P5 (GRU-B) base 164: +0..7 Wih[:,128:] (ig) [PERM], +8..15 Wih[:,64:128] (z) [PERM],
//   +16..23 Whh[:,64:128] (z) [nat], +24..27 bIG, +28..31 bZ
// P6 (dec) base 196: +0..7 dW1 [PERM], +8..9 dW2 [PERM], +10..13 db1, +14 db2
//
// PERM: layer input comes from in-kernel C-fragments. k-slot (kb,sg,j) holds input
// feature kb*32 + 16*(j>>2) + 4*sg + (j&3)  -> B-frag = lane-local repack of C regs.
#define NFRAG 211

__global__ __launch_bounds__(64) void prep_kernel(
    const float* __restrict__ pcW1, const float* __restrict__ pcb1, const float* __restrict__ pcW2, const float* __restrict__ pcb2,
    const float* __restrict__ fcW1, const float* __restrict__ fcb1, const float* __restrict__ fcW2, const float* __restrict__ fcb2,
    const float* __restrict__ ycW1, const float* __restrict__ ycb1, const float* __restrict__ ycW2, const float* __restrict__ ycb2,
    const float* __restrict__ ndW1, const float* __restrict__ ndb1, const float* __restrict__ ndW2, const float* __restrict__ ndb2,
    const float* __restrict__ Wih,  const float* __restrict__ bih,  const float* __restrict__ Whh,  const float* __restrict__ bhh,
    const float* __restrict__ dW1,  const float* __restrict__ db1,  const float* __restrict__ dW2,  const float* __restrict__ db2,
    char* __restrict__ ws)
{
    const int f = blockIdx.x, l = threadIdx.x;
    const int sg = l >> 4, c16 = l & 15;
    char* dst = ws + (size_t)f * 1024 + (size_t)l * 16;

    int kind = 0;                 // 0: bf16 weight frag, 1: f32 bias frag
    const float* W = nullptr; const float* B1 = nullptr; const float* B2 = nullptr;
    int t = 0, kb = 0, ncol = 64, coloff = 0, boff = 0, mlp = 0;
    bool msgmask = false, decw2 = false, db2frag = false, perm = false;

    if (f < 108) {
        const int m = f / 36, r = f % 36;
        const float* W1 = (m == 0 ? pcW1 : (m == 1 ? fcW1 : ycW1));
        const float* W2 = (m == 0 ? pcW2 : (m == 1 ? fcW2 : ycW2));
        const float* b1 = (m == 0 ? pcb1 : (m == 1 ? fcb1 : ycb1));
        const float* b2 = (m == 0 ? pcb2 : (m == 1 ? fcb2 : ycb2));
        if (r < 20)      { W = W1; kb = r >> 2; t = r & 3; msgmask = (kb == 4); mlp = m; }
        else if (r < 28) { W = W2; int rr = r - 20; kb = rr >> 2; t = rr & 3; perm = true; }
        else if (r < 32) { kind = 1; B1 = b1; t = r - 28; }
        else             { kind = 1; B1 = b2; t = r - 32; }
    } else if (f < 132) {
        const int r = f - 108;
        if (r < 8)       { W = ndW1; kb = r >> 2; t = r & 3; perm = true; }
        else if (r < 16) { W = ndW2; int rr = r - 8; kb = rr >> 2; t = rr & 3; perm = true; }
        else if (r < 20) { kind = 1; B1 = ndb1; t = r - 16; }
        else             { kind = 1; B1 = ndb2; t = r - 20; }
    } else if (f < 164) {
        const int r = f - 132; ncol = 192;
        if (r < 8)       { W = Whh; coloff = 128; kb = r >> 2; t = r & 3; }
        else if (r < 16) { W = Wih; coloff = 0;   int rr = r - 8;  kb = rr >> 2; t = rr & 3; perm = true; }
        else if (r < 24) { W = Whh; coloff = 0;   int rr = r - 16; kb = rr >> 2; t = rr & 3; }
        else if (r < 28) { kind = 1; B1 = bhh; boff = 128; t = r - 24; }
        else             { kind = 1; B1 = bih; B2 = bhh; boff = 0; t = r - 28; }
    } else if (f < 196) {
        const int r = f - 164; ncol = 192;
        if (r < 8)       { W = Wih; coloff = 128; kb = r >> 2; t = r & 3; perm = true; }
        else if (r < 16) { W = Wih; coloff = 64;  int rr = r - 8;  kb = rr >> 2; t = rr & 3; perm = true; }
        else if (r < 24) { W = Whh; coloff = 64;  int rr = r - 16; kb = rr >> 2; t = rr & 3; }
        else if (r < 28) { kind = 1; B1 = bih; boff = 128; t = r - 24; }
        else             { kind = 1; B1 = bih; B2 = bhh; boff = 64; t = r - 28; }
    } else {
        const int r = f - 196;
        if (r < 8)       { W = dW1; kb = r >> 2; t = r & 3; perm = true; }
        else if (r < 10) { W = dW2; kb = r - 8; t = 0; decw2 = true; perm = true; }
        else if (r < 14) { kind = 1; B1 = db1; t = r - 10; }
        else             { kind = 1; B1 = db2; t = 0; db2frag = true; }
    }

    if (!kind) {
        const int row = 16 * t + c16;
        bf8v v;
        #pragma unroll
        for (int j = 0; j < 8; ++j) {
            const int k = perm ? (kb * 32 + 16 * (j >> 2) + 4 * sg + (j & 3))
                               : (kb * 32 + sg * 8 + j);
            float x;
            if (msgmask) { const int kk = k - 128 - mlp * 4; x = (kk >= 0 && kk < 4) ? W[(128 + kk) * 64 + row] : 0.f; }
            else if (decw2) { x = (row < 4) ? W[k * 4 + row] : 0.f; }
            else { x = W[k * ncol + coloff + row]; }
            v[j] = (__bf16)x;
        }
        *(bf8v*)dst = v;
    } else {
        f4 o;
        #pragma unroll
        for (int r4 = 0; r4 < 4; ++r4) {
            float x;
            if (db2frag) { x = (sg == 0 && t == 0) ? B1[r4] : 0.f; }
            else {
                const int fi = boff + 16 * t + 4 * sg + r4;
                x = B1[fi]; if (B2) x += B2[fi];
            }
            o[r4] = x;
        }
        *(f4*)dst = o;
    }
}

// ---------------- LDS: weight phase buffer only ----------------
#define LDSZ 36864         // 36 frags x 1KB -> 4 blocks/CU capacity

__global__ __launch_bounds__(256, 2) void kgnn_main(
    const float* __restrict__ hx,  const float* __restrict__ pcm,
    const float* __restrict__ fcm, const float* __restrict__ ycm,
    const float* __restrict__ hy,
    const char*  __restrict__ ws,  float* __restrict__ out)
{
    __shared__ __align__(16) char LD[LDSZ];
    const int tid  = threadIdx.x;
    const int b    = blockIdx.x >> 5;
    const int tile = blockIdx.x & 31;
    const int n0   = tile * 128;
    const int baseH = b * 64 * NPOS;
    const int baseX = b * 4 * NPOS;

    const int lane = tid & 63, wid = tid >> 6;
    const int s = lane >> 4, q = lane & 15;
    const int Pv[2] = { wid * 32 + q, wid * 32 + 16 + q };
    const int Gn[2] = { n0 + Pv[0], n0 + Pv[1] };

    // natural B-frag from a [64][NPOS] f32 tensor: lane holds feats h*32+8s..+7 at pos gnq
    auto ldTB = [&](const float* __restrict__ T, int gnq, int h) -> bf8v {
        bf8v v;
        #pragma unroll
        for (int j = 0; j < 8; ++j)
            v[j] = (__bf16)T[baseH + (h * 32 + 8 * s + j) * NPOS + gnq];
        return v;
    };
    // lane-local C->B repack (PERM layers): B[h] = {a[2h][0..3], a[2h+1][0..3]}
    auto packB = [&](const f4* aa, int h, bool relu) -> bf8v {
        bf8v v;
        #pragma unroll
        for (int j = 0; j < 8; ++j) {
            float x = aa[2 * h + (j >> 2)][j & 3];
            if (relu) x = fmaxf(x, 0.f);
            v[j] = (__bf16)x;
        }
        return v;
    };

    // ---- hoisted global B-frags: hx[n] (used by 3 MLPs + GRU) and messages ----
    bf8v hxn0[2], hxn1[2], msgB[2];
    #pragma unroll
    for (int cc = 0; cc < 2; ++cc) {
        hxn0[cc] = ldTB(hx, Gn[cc], 0);
        hxn1[cc] = ldTB(hx, Gn[cc], 1);
        #pragma unroll
        for (int j = 0; j < 8; ++j) {
            const int idx = 8 * s + j;
            float x = 0.f;
            if      (idx < 4)  x = pcm[baseX + idx * NPOS + Gn[cc]];
            else if (idx < 8)  x = fcm[baseX + (idx - 4) * NPOS + Gn[cc]];
            else if (idx < 12) x = ycm[baseX + (idx - 8) * NPOS + Gn[cc]];
            msgB[cc][j] = (__bf16)x;
        }
    }

    auto stageW = [&](int gbase, int nf) {
        #pragma unroll
        for (int f0 = 0; f0 < 9; ++f0) {
            const int f = f0 * 4 + wid;
            if (f < nf) {
                f4 v = *(const f4*)(ws + ((size_t)(gbase + f) << 10) + ((size_t)lane << 4));
                *(f4*)(LD + (f << 10) + (lane << 4)) = v;
            }
        }
    };

    stageW(0, 36);                 // P0 weights
    __syncthreads();

    auto ldAL = [&](int fl) -> bf8v {
        return *(const bf8v*)(LD + (fl << 10) + (lane << 4));
    };
    auto ldBiasL = [&](int fl) -> f4 {
        return *(const f4*)(LD + (fl << 10) + (lane << 4));
    };

    // ======== P0/P1/P2: pc / fc / yc MLPs (register-chained) ========
    f4 sum3[2][4];
    #pragma unroll
    for (int m = 0; m < 3; ++m) {
        bf8v e0[2], e1[2];
        #pragma unroll
        for (int cc = 0; cc < 2; ++cc) {
            if (m == 0) {
                const int gm = (Gn[cc] == 0) ? 0 : Gn[cc] - 1;
                e0[cc] = ldTB(hx, gm, 0); e1[cc] = ldTB(hx, gm, 1);
            } else if (m == 1) {
                const int gp = (Gn[cc] == NPOS - 1) ? NPOS - 1 : Gn[cc] + 1;
                e0[cc] = ldTB(hx, gp, 0); e1[cc] = ldTB(hx, gp, 1);
            } else {
                e0[cc] = ldTB(hy, Gn[cc], 0); e1[cc] = ldTB(hy, Gn[cc], 1);
            }
        }
        f4 a[2][4];
        #pragma unroll
        for (int t = 0; t < 4; ++t) { f4 bv = ldBiasL(28 + t); a[0][t] = bv; a[1][t] = bv; }
        #pragma unroll
        for (int t = 0; t < 4; ++t) { bf8v A = ldAL(t);      a[0][t] = MF(A, e0[0],   a[0][t]); a[1][t] = MF(A, e0[1],   a[1][t]); }
        #pragma unroll
        for (int t = 0; t < 4; ++t) { bf8v A = ldAL(4 + t);  a[0][t] = MF(A, e1[0],   a[0][t]); a[1][t] = MF(A, e1[1],   a[1][t]); }
        #pragma unroll
        for (int t = 0; t < 4; ++t) { bf8v A = ldAL(8 + t);  a[0][t] = MF(A, hxn0[0], a[0][t]); a[1][t] = MF(A, hxn0[1], a[1][t]); }
        #pragma unroll
        for (int t = 0; t < 4; ++t) { bf8v A = ldAL(12 + t); a[0][t] = MF(A, hxn1[0], a[0][t]); a[1][t] = MF(A, hxn1[1], a[1][t]); }
        #pragma unroll
        for (int t = 0; t < 4; ++t) { bf8v A = ldAL(16 + t); a[0][t] = MF(A, msgB[0], a[0][t]); a[1][t] = MF(A, msgB[1], a[1][t]); }

        bf8v u0[2] = { packB(a[0], 0, true), packB(a[1], 0, true) };
        bf8v u1[2] = { packB(a[0], 1, true), packB(a[1], 1, true) };

        f4 a2[2][4];
        #pragma unroll
        for (int t = 0; t < 4; ++t) { f4 bv = ldBiasL(32 + t); a2[0][t] = bv; a2[1][t] = bv; }
        #pragma unroll
        for (int t = 0; t < 4; ++t) { bf8v A = ldAL(20 + t); a2[0][t] = MF(A, u0[0], a2[0][t]); a2[1][t] = MF(A, u0[1], a2[1][t]); }
        #pragma unroll
        for (int t = 0; t < 4; ++t) { bf8v A = ldAL(24 + t); a2[0][t] = MF(A, u1[0], a2[0][t]); a2[1][t] = MF(A, u1[1], a2[1][t]); }
        #pragma unroll
        for (int cc = 0; cc < 2; ++cc)
            #pragma unroll
            for (int t = 0; t < 4; ++t)
                #pragma unroll
                for (int r = 0; r < 4; ++r) {
                    float x = fmaxf(a2[cc][t][r], 0.f);
                    if (m == 0) sum3[cc][t][r] = x; else sum3[cc][t][r] += x;
                }
        __syncthreads();
        stageW(m == 0 ? 36 : (m == 1 ? 72 : 108), m == 2 ? 24 : 36);
        __syncthreads();
    }

    // ======== P3: nd MLP -> U (all-register) ========
    bf8v uu0[2], uu1[2];
    {
        bf8v v0[2] = { packB(sum3[0], 0, false), packB(sum3[1], 0, false) };
        bf8v v1[2] = { packB(sum3[0], 1, false), packB(sum3[1], 1, false) };
        f4 a[2][4];
        #pragma unroll
        for (int t = 0; t < 4; ++t) { f4 bv = ldBiasL(16 + t); a[0][t] = bv; a[1][t] = bv; }
        #pragma unroll
        for (int t = 0; t < 4; ++t) { bf8v A = ldAL(t);     a[0][t] = MF(A, v0[0], a[0][t]); a[1][t] = MF(A, v0[1], a[1][t]); }
        #pragma unroll
        for (int t = 0; t < 4; ++t) { bf8v A = ldAL(4 + t); a[0][t] = MF(A, v1[0], a[0][t]); a[1][t] = MF(A, v1[1], a[1][t]); }
        bf8v w0[2] = { packB(a[0], 0, true), packB(a[1], 0, true) };
        bf8v w1[2] = { packB(a[0], 1, true), packB(a[1], 1, true) };
        f4 a2[2][4];
        #pragma unroll
        for (int t = 0; t < 4; ++t) { f4 bv = ldBiasL(20 + t); a2[0][t] = bv; a2[1][t] = bv; }
        #pragma unroll
        for (int t = 0; t < 4; ++t) { bf8v A = ldAL(8 + t);  a2[0][t] = MF(A, w0[0], a2[0][t]); a2[1][t] = MF(A, w0[1], a2[1][t]); }
        #pragma unroll
        for (int t = 0; t < 4; ++t) { bf8v A = ldAL(12 + t); a2[0][t] = MF(A, w1[0], a2[0][t]); a2[1][t] = MF(A, w1[1], a2[1][t]); }
        uu0[0] = packB(a2[0], 0, true); uu0[1] = packB(a2[1], 0, true);
        uu1[0] = packB(a2[0], 1, true); uu1[1] = packB(a2[1], 1, true);
    }
    __syncthreads();
    stageW(132, 32);               // P4 GRU-A
    __syncthreads();

    // ======== P4: GRU-A: g = sigm(r) * hg ========
    f4 g[2][4];
    {
        #pragma unroll
        for (int t = 0; t < 4; ++t) { f4 bv = ldBiasL(24 + t); g[0][t] = bv; g[1][t] = bv; }
        #pragma unroll
        for (int t = 0; t < 4; ++t) { bf8v A = ldAL(t);     g[0][t] = MF(A, hxn0[0], g[0][t]); g[1][t] = MF(A, hxn0[1], g[1][t]); }
        #pragma unroll
        for (int t = 0; t < 4; ++t) { bf8v A = ldAL(4 + t); g[0][t] = MF(A, hxn1[0], g[0][t]); g[1][t] = MF(A, hxn1[1], g[1][t]); }
        f4 rr[2][4];
        #pragma unroll
        for (int t = 0; t < 4; ++t) { f4 bv = ldBiasL(28 + t); rr[0][t] = bv; rr[1][t] = bv; }
        #pragma unroll
        for (int t = 0; t < 4; ++t) { bf8v A = ldAL(8 + t);  rr[0][t] = MF(A, uu0[0], rr[0][t]); rr[1][t] = MF(A, uu0[1], rr[1][t]); }
        #pragma unroll
        for (int t = 0; t < 4; ++t) { bf8v A = ldAL(12 + t); rr[0][t] = MF(A, uu1[0], rr[0][t]); rr[1][t] = MF(A, uu1[1], rr[1][t]); }
        #pragma unroll
        for (int t = 0; t < 4; ++t) { bf8v A = ldAL(16 + t); rr[0][t] = MF(A, hxn0[0], rr[0][t]); rr[1][t] = MF(A, hxn0[1], rr[1][t]); }
        #pragma unroll
        for (int t = 0; t < 4; ++t) { bf8v A = ldAL(20 + t); rr[0][t] = MF(A, hxn1[0], rr[0][t]); rr[1][t] = MF(A, hxn1[1], rr[1][t]); }
        #pragma unroll
        for (int cc = 0; cc < 2; ++cc)
            #pragma unroll
            for (int t = 0; t < 4; ++t)
                #pragma unroll
                for (int r = 0; r < 4; ++r) g[cc][t][r] = sigm(rr[cc][t][r]) * g[cc][t][r];
    }
    __syncthreads();
    stageW(164, 32);               // P5 GRU-B
    __syncthreads();

    // ======== P5: GRU-B: n = tanh(ig + g); z; hnew ========
    bf8v hnB0[2], hnB1[2];
    {
        // hprev (C layout, f32) issued early to hide latency under the MFMAs below
        f4 hpv[2][4];
        #pragma unroll
        for (int cc = 0; cc < 2; ++cc)
            #pragma unroll
            for (int t = 0; t < 4; ++t)
                #pragma unroll
                for (int r = 0; r < 4; ++r)
                    hpv[cc][t][r] = hx[baseH + (16 * t + 4 * s + r) * NPOS + Gn[cc]];

        f4 gi[2][4];
        #pragma unroll
        for (int t = 0; t < 4; ++t) { f4 bv = ldBiasL(24 + t); gi[0][t] = bv; gi[1][t] = bv; }
        #pragma unroll
        for (int t = 0; t < 4; ++t) { bf8v A = ldAL(t);     gi[0][t] = MF(A, uu0[0], gi[0][t]); gi[1][t] = MF(A, uu0[1], gi[1][t]); }
        #pragma unroll
        for (int t = 0; t < 4; ++t) { bf8v A = ldAL(4 + t); gi[0][t] = MF(A, uu1[0], gi[0][t]); gi[1][t] = MF(A, uu1[1], gi[1][t]); }
        #pragma unroll
        for (int cc = 0; cc < 2; ++cc)
            #pragma unroll
            for (int t = 0; t < 4; ++t)
                #pragma unroll
                for (int r = 0; r < 4; ++r) g[cc][t][r] = tanh_f(gi[cc][t][r] + g[cc][t][r]);

        f4 zz[2][4];
        #pragma unroll
        for (int t = 0; t < 4; ++t) { f4 bv = ldBiasL(28 + t); zz[0][t] = bv; zz[1][t] = bv; }
        #pragma unroll
        for (int t = 0; t < 4; ++t) { bf8v A = ldAL(8 + t);  zz[0][t] = MF(A, uu0[0], zz[0][t]); zz[1][t] = MF(A, uu0[1], zz[1][t]); }
        #pragma unroll
        for (int t = 0; t < 4; ++t) { bf8v A = ldAL(12 + t); zz[0][t] = MF(A, uu1[0], zz[0][t]); zz[1][t] = MF(A, uu1[1], zz[1][t]); }
        #pragma unroll
        for (int t = 0; t < 4; ++t) { bf8v A = ldAL(16 + t); zz[0][t] = MF(A, hxn0[0], zz[0][t]); zz[1][t] = MF(A, hxn0[1], zz[1][t]); }
        #pragma unroll
        for (int t = 0; t < 4; ++t) { bf8v A = ldAL(20 + t); zz[0][t] = MF(A, hxn1[0], zz[0][t]); zz[1][t] = MF(A, hxn1[1], zz[1][t]); }

        float* __restrict__ outH = out + NB * 4 * NPOS + baseH;
        f4 hn[2][4];
        #pragma unroll
        for (int cc = 0; cc < 2; ++cc)
            #pragma unroll
            for (int t = 0; t < 4; ++t)
                #pragma unroll
                for (int r = 0; r < 4; ++r) {
                    float z  = sigm(zz[cc][t][r]);
                    float nn = g[cc][t][r];
                    float hv = nn + z * (hpv[cc][t][r] - nn);
                    hn[cc][t][r] = hv;
                    outH[(16 * t + 4 * s + r) * NPOS + Gn[cc]] = hv;
                }
        hnB0[0] = packB(hn[0], 0, false); hnB0[1] = packB(hn[1], 0, false);
        hnB1[0] = packB(hn[0], 1, false); hnB1[1] = packB(hn[1], 1, false);
    }
    __syncthreads();
    stageW(196, 15);               // P6 dec
    __syncthreads();

    // ======== P6: decoder ========
    {
        f4 a[2][4];
        #pragma unroll
        for (int t = 0; t < 4; ++t) { f4 bv = ldBiasL(10 + t); a[0][t] = bv; a[1][t] = bv; }
        #pragma unroll
        for (int t = 0; t < 4; ++t) { bf8v A = ldAL(t);     a[0][t] = MF(A, hnB0[0], a[0][t]); a[1][t] = MF(A, hnB0[1], a[1][t]); }
        #pragma unroll
        for (int t = 0; t < 4; ++t) { bf8v A = ldAL(4 + t); a[0][t] = MF(A, hnB1[0], a[0][t]); a[1][t] = MF(A, hnB1[1], a[1][t]); }
        bf8v e0[2] = { packB(a[0], 0, true), packB(a[1], 0, true) };
        bf8v e1[2] = { packB(a[0], 1, true), packB(a[1], 1, true) };
        f4 ep[2];
        { f4 bv = ldBiasL(14); ep[0] = bv; ep[1] = bv; }
        { bf8v A = ldAL(8); ep[0] = MF(A, e0[0], ep[0]); ep[1] = MF(A, e0[1], ep[1]); }
        { bf8v A = ldAL(9); ep[0] = MF(A, e1[0], ep[0]); ep[1] = MF(A, e1[1], ep[1]); }
        if (s == 0) {
            #pragma unroll
            for (int cc = 0; cc < 2; ++cc) {
                #pragma unroll
                for (int r = 0; r < 4; ++r) out[baseX + r * NPOS + Gn[cc]] = ep[cc][r];
            }
        }
    }
}

extern "C" void kernel_launch(void* const* d_in, const int* in_sizes, int n_in,
                              void* d_out, int out_size, void* d_ws, size_t ws_size,
                              hipStream_t stream) {
    const float* hx   = (const float*)d_in[0];
    const float* pcm  = (const float*)d_in[1];
    const float* fcm  = (const float*)d_in[2];
    const float* ycm  = (const float*)d_in[3];
    const float* hy   = (const float*)d_in[4];

    prep_kernel<<<dim3(NFRAG), dim3(64), 0, stream>>>(
        (const float*)d_in[5],  (const float*)d_in[6],  (const float*)d_in[7],  (const float*)d_in[8],
        (const float*)d_in[9],  (const float*)d_in[10], (const float*)d_in[11], (const float*)d_in[12],
        (const float*)d_in[13], (const float*)d_in[14], (const float*)d_in[15], (const float*)d_in[16],
        (const float*)d_in[17], (const float*)d_in[18], (const float*)d_in[19], (const float*)d_in[20],
        (const float*)d_in[21], (const float*)d_in[22], (const float*)d_in[23], (const float*)d_in[24],
        (const float*)d_in[25], (const float*)d_in[26], (const float*)d_in[27], (const float*)d_in[28],
        (char*)d_ws);

    kgnn_main<<<dim3(NB * 32), dim3(256), 0, stream>>>(
        hx, pcm, fcm, ycm, hy, (const char*)d_ws, (float*)d_out);
}